// Round 10
// baseline (340.548 us; speedup 1.0000x reference)
//
#include <hip/hip_runtime.h>
#include <cstdint>

#define B_   8
#define CIN  64
#define DIM_ 256
#define H_   128
#define W_   128
#define HW_  (H_*W_)

typedef unsigned short u16;
typedef unsigned int   u32;
typedef short short8 __attribute__((ext_vector_type(8)));
typedef float f32x4  __attribute__((ext_vector_type(4)));

__device__ __forceinline__ u16 f2bf(float f) {
    u32 u = __float_as_uint(f);
    u32 r = (u + 0x7fffu + ((u >> 16) & 1u)) >> 16;
    return (u16)r;
}
__device__ __forceinline__ float bf2f(u16 h) {
    return __uint_as_float(((u32)h) << 16);
}

// ---------------------------------------------------------------------------
// conv1x1 as bf16 MFMA GEMM (R5 proven version, 48KB LDS, for x->pre, y->pre)
// ---------------------------------------------------------------------------
__global__ __launch_bounds__(256) void conv_mfma_kernel(
    const float* __restrict__ in, const float* __restrict__ Wc,
    u16* __restrict__ pre)
{
    __shared__ u16 Alds[256 * 64];
    __shared__ u16 Blds[128 * 64];

    const int tid = threadIdx.x;
    const int b = blockIdx.y;
    const int px0 = blockIdx.x * 128;

    {
        const int row = tid;
        const float* wp = Wc + (size_t)row * 64;
        #pragma unroll
        for (int s = 0; s < 8; ++s) {
            float4 f0 = *(const float4*)(wp + s * 8);
            float4 f1 = *(const float4*)(wp + s * 8 + 4);
            uint4 pk;
            pk.x = f2bf(f0.x) | ((u32)f2bf(f0.y) << 16);
            pk.y = f2bf(f0.z) | ((u32)f2bf(f0.w) << 16);
            pk.z = f2bf(f1.x) | ((u32)f2bf(f1.y) << 16);
            pk.w = f2bf(f1.z) | ((u32)f2bf(f1.w) << 16);
            *(uint4*)&Alds[row * 64 + ((s * 8) ^ ((row & 7) << 3))] = pk;
        }
    }
    #pragma unroll
    for (int v4 = 0; v4 < 4; ++v4) {
        int it = tid + v4 * 256;
        int px = it & 127, cg = it >> 7;
        const float* sp = in + ((size_t)b * CIN + cg * 8) * HW_ + px0 + px;
        u32 wv[4];
        #pragma unroll
        for (int j = 0; j < 4; ++j) {
            float a = sp[(size_t)(2 * j) * HW_];
            float c = sp[(size_t)(2 * j + 1) * HW_];
            wv[j] = f2bf(a) | ((u32)f2bf(c) << 16);
        }
        *(uint4*)&Blds[px * 64 + ((cg * 8) ^ ((px & 7) << 3))] =
            make_uint4(wv[0], wv[1], wv[2], wv[3]);
    }
    __syncthreads();

    const int lane = tid & 63, wid = tid >> 6;
    const int g = lane >> 4, ln = lane & 15;
    const int m0 = wid * 64;
    f32x4 acc[4][8] = {};

    #pragma unroll
    for (int ks = 0; ks < 2; ++ks) {
        short8 af[4];
        #pragma unroll
        for (int fm = 0; fm < 4; ++fm) {
            int m = m0 + fm * 16 + ln;
            af[fm] = *(const short8*)&Alds[m * 64 + ((ks * 32 + g * 8) ^ ((m & 7) << 3))];
        }
        #pragma unroll
        for (int fn = 0; fn < 8; ++fn) {
            int p = fn * 16 + ln;
            short8 bf = *(const short8*)&Blds[p * 64 + ((ks * 32 + g * 8) ^ ((p & 7) << 3))];
            #pragma unroll
            for (int fm = 0; fm < 4; ++fm)
                acc[fm][fn] = __builtin_amdgcn_mfma_f32_16x16x32_bf16(af[fm], bf, acc[fm][fn], 0, 0, 0);
        }
    }

    u16* op = pre + (size_t)b * DIM_ * HW_;
    #pragma unroll
    for (int fm = 0; fm < 4; ++fm)
        #pragma unroll
        for (int fn = 0; fn < 8; ++fn)
            #pragma unroll
            for (int r = 0; r < 4; ++r) {
                int ch = m0 + fm * 16 + g * 4 + r;
                op[(size_t)ch * HW_ + px0 + fn * 16 + ln] = f2bf(acc[fm][fn][r]);
            }
}

// ---------------------------------------------------------------------------
// conv_t (R7 verified): same conv, output TRANSPOSED preT[b][px][256] bf16.
// ---------------------------------------------------------------------------
__global__ __launch_bounds__(256) void conv_mfma_t_kernel(
    const float* __restrict__ in, const float* __restrict__ Wc,
    u16* __restrict__ preT)
{
    __shared__ u16 S[128 * 264];          // 67.6 KB

    u16* Alds = S;
    u16* Blds = S + 16384;

    const int tid = threadIdx.x;
    const int b = blockIdx.y;
    const int px0 = blockIdx.x * 128;

    {
        const int row = tid;
        const float* wp = Wc + (size_t)row * 64;
        #pragma unroll
        for (int s = 0; s < 8; ++s) {
            float4 f0 = *(const float4*)(wp + s * 8);
            float4 f1 = *(const float4*)(wp + s * 8 + 4);
            uint4 pk;
            pk.x = f2bf(f0.x) | ((u32)f2bf(f0.y) << 16);
            pk.y = f2bf(f0.z) | ((u32)f2bf(f0.w) << 16);
            pk.z = f2bf(f1.x) | ((u32)f2bf(f1.y) << 16);
            pk.w = f2bf(f1.z) | ((u32)f2bf(f1.w) << 16);
            *(uint4*)&Alds[row * 64 + ((s * 8) ^ ((row & 7) << 3))] = pk;
        }
    }
    #pragma unroll
    for (int v4 = 0; v4 < 4; ++v4) {
        int it = tid + v4 * 256;
        int px = it & 127, cg = it >> 7;
        const float* sp = in + ((size_t)b * CIN + cg * 8) * HW_ + px0 + px;
        u32 wv[4];
        #pragma unroll
        for (int j = 0; j < 4; ++j) {
            float a = sp[(size_t)(2 * j) * HW_];
            float c = sp[(size_t)(2 * j + 1) * HW_];
            wv[j] = f2bf(a) | ((u32)f2bf(c) << 16);
        }
        *(uint4*)&Blds[px * 64 + ((cg * 8) ^ ((px & 7) << 3))] =
            make_uint4(wv[0], wv[1], wv[2], wv[3]);
    }
    __syncthreads();

    const int lane = tid & 63, wid = tid >> 6;
    const int g = lane >> 4, ln = lane & 15;
    const int m0 = wid * 64;
    f32x4 acc[4][8] = {};

    #pragma unroll
    for (int ks = 0; ks < 2; ++ks) {
        short8 af[4];
        #pragma unroll
        for (int fm = 0; fm < 4; ++fm) {
            int m = m0 + fm * 16 + ln;
            af[fm] = *(const short8*)&Alds[m * 64 + ((ks * 32 + g * 8) ^ ((m & 7) << 3))];
        }
        #pragma unroll
        for (int fn = 0; fn < 8; ++fn) {
            int p = fn * 16 + ln;
            short8 bf = *(const short8*)&Blds[p * 64 + ((ks * 32 + g * 8) ^ ((p & 7) << 3))];
            #pragma unroll
            for (int fm = 0; fm < 4; ++fm)
                acc[fm][fn] = __builtin_amdgcn_mfma_f32_16x16x32_bf16(af[fm], bf, acc[fm][fn], 0, 0, 0);
        }
    }
    __syncthreads();   // staging dead; reuse S as [128 px][264] transpose buf

    #pragma unroll
    for (int fm = 0; fm < 4; ++fm)
        #pragma unroll
        for (int fn = 0; fn < 8; ++fn) {
            int px = fn * 16 + ln;
            int ch0 = m0 + fm * 16 + g * 4;
            int idx = px * 264 + ((ch0 + 8 * ((px >> 3) & 7)) & 255);
            u32 a0 = f2bf(acc[fm][fn][0]) | ((u32)f2bf(acc[fm][fn][1]) << 16);
            u32 a1 = f2bf(acc[fm][fn][2]) | ((u32)f2bf(acc[fm][fn][3]) << 16);
            *(uint2*)&S[idx] = make_uint2(a0, a1);
        }
    __syncthreads();

    {
        int px = tid >> 1, half = tid & 1;
        int rot = 8 * ((px >> 3) & 7);
        u16* dst = preT + ((size_t)b * HW_ + px0 + px) * 256 + half * 128;
        #pragma unroll
        for (int s = 0; s < 16; ++s) {
            int ch = half * 128 + s * 8;
            *(uint4*)(dst + s * 8) = *(const uint4*)&S[px * 264 + ((ch + rot) & 255)];
        }
    }
}

// ---------------------------------------------------------------------------
// dw (unchanged, for q,k): depthwise 3x3 on [ch][px] layout
// ---------------------------------------------------------------------------
__global__ __launch_bounds__(256) void dw_kernel(
    const u16* __restrict__ pre, const float* __restrict__ Wd,
    u16* __restrict__ dst)
{
    __shared__ u16 t0[34][144];

    const int tid = threadIdx.x;
    const int y0 = blockIdx.x * 32;
    const int ch = blockIdx.y;
    const int b = blockIdx.z;
    const u16* src = pre + ((size_t)b * DIM_ + ch) * HW_;

    for (int i = tid; i < 68; i += 256)
        t0[i >> 1][(i & 1) ? 136 : 7] = 0;
    for (int i = tid; i < 544; i += 256) {
        int row = i >> 4, seg = i & 15;
        int gy = y0 - 1 + row;
        uint4 v = make_uint4(0, 0, 0, 0);
        if (gy >= 0 && gy < H_) v = *(const uint4*)(src + (size_t)gy * W_ + seg * 8);
        *(uint4*)&t0[row][8 + seg * 8] = v;
    }
    const float* wv = Wd + (size_t)ch * 9;
    float w00 = wv[0], w01 = wv[1], w02 = wv[2];
    float w10 = wv[3], w11 = wv[4], w12 = wv[5];
    float w20 = wv[6], w21 = wv[7], w22 = wv[8];
    __syncthreads();

    const int px = tid & 127, half = tid >> 7;
    u16* op = dst + ((size_t)b * DIM_ + ch) * HW_;
    float h0m2 = 0.f, h0m1 = 0.f, h1m1 = 0.f;
    #pragma unroll
    for (int y = 0; y < 18; ++y) {
        int r = half * 16 + y;
        float v0 = bf2f(t0[r][7 + px]);
        float v1 = bf2f(t0[r][8 + px]);
        float v2 = bf2f(t0[r][9 + px]);
        float h0 = fmaf(v0, w00, fmaf(v1, w01, v2 * w02));
        float h1 = fmaf(v0, w10, fmaf(v1, w11, v2 * w12));
        float h2 = fmaf(v0, w20, fmaf(v1, w21, v2 * w22));
        if (y >= 2)
            op[(size_t)(y0 + half * 16 + y - 2) * W_ + px] = f2bf(h0m2 + h1m1 + h2);
        h0m2 = h0m1; h0m1 = h0; h1m1 = h1;
    }
}

// ---------------------------------------------------------------------------
// dwt2 (NEW): depthwise 3x3 in transposed space, LDS-tiled.
// In: preT[b][px][256]. Out: vTs[(b*4+kc)*HW + px][64], XOR-swizzled columns
// (chg ^ (px&7)) so final7 can verbatim-copy rows into its fragment LDS.
// grid (64 tiles 16x16, 4 kc, 8 b), block 256.
// ---------------------------------------------------------------------------
__global__ __launch_bounds__(256) void dwt2_kernel(
    const u16* __restrict__ preT, const float* __restrict__ Wd,
    u16* __restrict__ vTs)
{
    __shared__ u16 t0[324 * 72];       // 18x18 halo x 64ch, px-stride 72 (align+banks)
    __shared__ float wlds[9 * 68];

    const int tid = threadIdx.x;
    const int tile = blockIdx.x;
    const int kc = blockIdx.y;
    const int b = blockIdx.z;
    const int y0 = (tile >> 3) * 16;
    const int x0 = (tile & 7) * 16;

    for (int i = tid; i < 576; i += 256) {
        int tap = i >> 6, c = i & 63;
        wlds[tap * 68 + c] = Wd[(size_t)(kc * 64 + c) * 9 + tap];
    }
    for (int it = tid; it < 2592; it += 256) {
        int pos = it >> 3, chg = it & 7;
        int py = pos / 18, pxi = pos - py * 18;
        int gy = y0 - 1 + py, gx = x0 - 1 + pxi;
        uint4 v = make_uint4(0, 0, 0, 0);
        if (gy >= 0 && gy < H_ && gx >= 0 && gx < W_)
            v = *(const uint4*)(preT + ((size_t)b * HW_ + (size_t)gy * W_ + gx) * 256 + kc * 64 + chg * 8);
        *(uint4*)&t0[pos * 72 + chg * 8] = v;
    }
    __syncthreads();

    const int chg = tid & 7, pg = tid >> 3;
    float w[9][8];
    #pragma unroll
    for (int tap = 0; tap < 9; ++tap) {
        float4 a = *(const float4*)&wlds[tap * 68 + chg * 8];
        float4 c4 = *(const float4*)&wlds[tap * 68 + chg * 8 + 4];
        w[tap][0] = a.x;  w[tap][1] = a.y;  w[tap][2] = a.z;  w[tap][3] = a.w;
        w[tap][4] = c4.x; w[tap][5] = c4.y; w[tap][6] = c4.z; w[tap][7] = c4.w;
    }
    u16* vb = vTs + ((size_t)(b * 4 + kc)) * HW_ * 64;
    #pragma unroll
    for (int j = 0; j < 8; ++j) {
        int lpx = pg * 8 + j;
        int ox = lpx & 15, oy = lpx >> 4;
        float acc[8] = {};
        #pragma unroll
        for (int dy = 0; dy < 3; ++dy)
            #pragma unroll
            for (int dx = 0; dx < 3; ++dx) {
                uint4 raw = *(const uint4*)&t0[((oy + dy) * 18 + ox + dx) * 72 + chg * 8];
                int tap = dy * 3 + dx;
                #pragma unroll
                for (int e = 0; e < 4; ++e) {
                    u32 wrd = ((const u32*)&raw)[e];
                    acc[2 * e]     = fmaf(w[tap][2 * e],     __uint_as_float(wrd << 16), acc[2 * e]);
                    acc[2 * e + 1] = fmaf(w[tap][2 * e + 1], __uint_as_float(wrd & 0xffff0000u), acc[2 * e + 1]);
                }
            }
        uint4 pk;
        pk.x = f2bf(acc[0]) | ((u32)f2bf(acc[1]) << 16);
        pk.y = f2bf(acc[2]) | ((u32)f2bf(acc[3]) << 16);
        pk.z = f2bf(acc[4]) | ((u32)f2bf(acc[5]) << 16);
        pk.w = f2bf(acc[6]) | ((u32)f2bf(acc[7]) << 16);
        size_t px = (size_t)(y0 + oy) * W_ + x0 + ox;
        *(uint4*)(vb + px * 64 + ((chg ^ (ox & 7)) << 3)) = pk;
    }
}

// ---------------------------------------------------------------------------
// Gram via MFMA (verified): direct global fragments, sumsq = diagonals
// ---------------------------------------------------------------------------
__global__ __launch_bounds__(256) void gram_mfma_kernel(
    const u16* __restrict__ q, const u16* __restrict__ k,
    float* __restrict__ pgram, float* __restrict__ pssq, float* __restrict__ pssk)
{
    __shared__ float red[4][1024];
    __shared__ float redq[4][32];
    __shared__ float redk[4][32];

    const int bh = blockIdx.y;
    const int chunk = blockIdx.x;
    const int tid = threadIdx.x;
    const int lane = tid & 63, wid = tid >> 6;
    const int g = lane >> 4, ln = lane & 15;

    const size_t off = (size_t)(bh * 32 + ln) * HW_ + chunk * 2048 + wid * 512 + g * 8;
    const u16* qp = q + off;
    const u16* kp = k + off;

    f32x4 aqk[2][2] = {};
    f32x4 aqq[2] = {};
    f32x4 akk[2] = {};

    #pragma unroll 4
    for (int n = 0; n < 512; n += 32) {
        short8 qf[2], kf[2];
        qf[0] = *(const short8*)(qp + n);
        qf[1] = *(const short8*)(qp + (size_t)16 * HW_ + n);
        kf[0] = *(const short8*)(kp + n);
        kf[1] = *(const short8*)(kp + (size_t)16 * HW_ + n);
        #pragma unroll
        for (int ti = 0; ti < 2; ++ti)
            #pragma unroll
            for (int tj = 0; tj < 2; ++tj)
                aqk[ti][tj] = __builtin_amdgcn_mfma_f32_16x16x32_bf16(qf[ti], kf[tj], aqk[ti][tj], 0, 0, 0);
        #pragma unroll
        for (int ti = 0; ti < 2; ++ti) {
            aqq[ti] = __builtin_amdgcn_mfma_f32_16x16x32_bf16(qf[ti], qf[ti], aqq[ti], 0, 0, 0);
            akk[ti] = __builtin_amdgcn_mfma_f32_16x16x32_bf16(kf[ti], kf[ti], akk[ti], 0, 0, 0);
        }
    }

    #pragma unroll
    for (int ti = 0; ti < 2; ++ti)
        #pragma unroll
        for (int tj = 0; tj < 2; ++tj)
            #pragma unroll
            for (int r = 0; r < 4; ++r)
                red[wid][(ti * 16 + g * 4 + r) * 32 + tj * 16 + ln] = aqk[ti][tj][r];
    if ((ln >> 2) == g) {
        #pragma unroll
        for (int ti = 0; ti < 2; ++ti) {
            redq[wid][ti * 16 + ln] = aqq[ti][ln & 3];
            redk[wid][ti * 16 + ln] = akk[ti][ln & 3];
        }
    }
    __syncthreads();

    for (int p = tid; p < 1024; p += 256) {
        float s = red[0][p] + red[1][p] + red[2][p] + red[3][p];
        pgram[((size_t)bh * 8 + chunk) * 1024 + p] = s;
    }
    if (tid < 32) {
        pssq[((size_t)bh * 8 + chunk) * 32 + tid] =
            redq[0][tid] + redq[1][tid] + redq[2][tid] + redq[3][tid];
    } else if (tid < 64) {
        int j = tid & 31;
        pssk[((size_t)bh * 8 + chunk) * 32 + j] =
            redk[0][j] + redk[1][j] + redk[2][j] + redk[3][j];
    }
}

// ---------------------------------------------------------------------------
// reduce partials -> normalize -> softmax -> Amm(bf16) = Wproj_h @ attn
// ---------------------------------------------------------------------------
__global__ __launch_bounds__(256) void softproj_kernel(
    const float* __restrict__ pgram, const float* __restrict__ pssq,
    const float* __restrict__ pssk, const float* __restrict__ Wproj,
    const float* __restrict__ temp, u16* __restrict__ Amm)
{
    __shared__ float att[32][33];
    __shared__ float nq[32], nk[32];

    const int bh = blockIdx.x;
    const int h = bh & 7;
    const int b = bh >> 3;
    const int tid = threadIdx.x;

    for (int p = tid; p < 1024; p += 256) {
        float s = 0.f;
        #pragma unroll
        for (int c = 0; c < 8; ++c) s += pgram[((size_t)bh * 8 + c) * 1024 + p];
        att[p >> 5][p & 31] = s;
    }
    if (tid < 32) {
        float s = 0.f;
        #pragma unroll
        for (int c = 0; c < 8; ++c) s += pssq[((size_t)bh * 8 + c) * 32 + tid];
        nq[tid] = fmaxf(sqrtf(s), 1e-12f);
    } else if (tid < 64) {
        int i = tid & 31;
        float s = 0.f;
        #pragma unroll
        for (int c = 0; c < 8; ++c) s += pssk[((size_t)bh * 8 + c) * 32 + i];
        nk[i] = fmaxf(sqrtf(s), 1e-12f);
    }
    __syncthreads();

    const float T = temp[h];
    if (tid < 32) {
        int i = tid;
        float row[32];
        float mx = -1e30f;
        float qi = T / nq[i];
        #pragma unroll
        for (int j = 0; j < 32; ++j) {
            float v = att[i][j] * qi / nk[j];
            row[j] = v;
            mx = fmaxf(mx, v);
        }
        float s = 0.f;
        #pragma unroll
        for (int j = 0; j < 32; ++j) { float e = expf(row[j] - mx); row[j] = e; s += e; }
        float inv = 1.f / s;
        #pragma unroll
        for (int j = 0; j < 32; ++j) att[i][j] = row[j] * inv;
    }
    __syncthreads();

    const int o = tid;
    float wp[32];
    #pragma unroll
    for (int i2 = 0; i2 < 32; i2 += 4)
        *(float4*)&wp[i2] = *(const float4*)&Wproj[(size_t)o * DIM_ + h * 32 + i2];
    u16* arow = Amm + ((size_t)b * DIM_ + o) * DIM_ + h * 32;
    #pragma unroll
    for (int j = 0; j < 32; ++j) {
        float s = 0.f;
        #pragma unroll
        for (int i = 0; i < 32; ++i) s = fmaf(wp[i], att[i][j], s);
        arow[j] = f2bf(s);
    }
}

// ---------------------------------------------------------------------------
// cast Wfus [256][192] fp32 -> bf16 (once)
// ---------------------------------------------------------------------------
__global__ __launch_bounds__(256) void wfus_cast_kernel(
    const float* __restrict__ Wfus, u16* __restrict__ Afus)
{
    int idx = blockIdx.x * 256 + threadIdx.x;
    int base = idx * 8;
    float4 f0 = *(const float4*)(Wfus + base);
    float4 f1 = *(const float4*)(Wfus + base + 4);
    uint4 pk;
    pk.x = f2bf(f0.x) | ((u32)f2bf(f0.y) << 16);
    pk.y = f2bf(f0.z) | ((u32)f2bf(f0.w) << 16);
    pk.z = f2bf(f1.x) | ((u32)f2bf(f1.y) << 16);
    pk.w = f2bf(f1.z) | ((u32)f2bf(f1.w) << 16);
    *(uint4*)(Afus + base) = pk;
}

// ---------------------------------------------------------------------------
// final7: v chunks via WIDE verbatim copy from pre-swizzled vTs;
// xyz chunks via proven scalar+swizzle path; wide float4 store epilogue
// through LDS-reuse. grid (128 px-panels, 2 o-groups, 8 b).
// ---------------------------------------------------------------------------
#define LOADB_F7(KC, WV, WX) do {                                               \
    if ((KC) < 4) {                                                             \
        const u16* vb_ = vTs + ((size_t)(b * 4 + (KC)) * HW_ + px0) * 64;       \
        _Pragma("unroll") for (int i_ = 0; i_ < 4; ++i_)                        \
            WV[i_] = *(const uint4*)(vb_ + (size_t)(i_ * 256 + tid) * 8);       \
    } else {                                                                    \
        const float* bp_ = ((KC) == 4) ? xin : ((KC) == 5) ? yin : zin;         \
        _Pragma("unroll") for (int i_ = 0; i_ < 2; ++i_) {                      \
            const float* sp_ = bp_ + ((size_t)b * CIN + (qq0 + 2 * i_) * 16) * HW_ + px0 + pxu; \
            _Pragma("unroll") for (int jj_ = 0; jj_ < 8; ++jj_)                 \
                WX[i_][jj_] = (u32)f2bf(sp_[(size_t)(2 * jj_) * HW_])           \
                           | ((u32)f2bf(sp_[(size_t)(2 * jj_ + 1) * HW_]) << 16); \
        }                                                                       \
    } } while (0)

#define WRITEB_F7(KC, BUF, WV, WX) do {                                         \
    if ((KC) < 4) {                                                             \
        _Pragma("unroll") for (int i_ = 0; i_ < 4; ++i_)                        \
            *(uint4*)&Bl[BUF][(size_t)(i_ * 256 + tid) * 8] = WV[i_];           \
    } else {                                                                    \
        u16* dd_ = &Bl[BUF][pxu * 64];                                          \
        _Pragma("unroll") for (int i_ = 0; i_ < 2; ++i_) {                      \
            int qq_ = qq0 + 2 * i_;                                             \
            *(uint4*)&dd_[(qq_ * 16)     ^ ((pxu & 7) << 3)] = make_uint4(WX[i_][0], WX[i_][1], WX[i_][2], WX[i_][3]); \
            *(uint4*)&dd_[(qq_ * 16 + 8) ^ ((pxu & 7) << 3)] = make_uint4(WX[i_][4], WX[i_][5], WX[i_][6], WX[i_][7]); \
        }                                                                       \
    } } while (0)

#define LOADA_F7(KC, A) do {                                                    \
    _Pragma("unroll") for (int ks_ = 0; ks_ < 2; ++ks_)                         \
    _Pragma("unroll") for (int fm_ = 0; fm_ < 2; ++fm_) {                       \
        int m_ = m0 + fm_ * 16 + ln;                                            \
        const u16* ap_ = ((KC) < 4)                                             \
            ? Amm + ((size_t)b * DIM_ + m_) * DIM_ + (KC) * 64 + ks_ * 32 + g * 8 \
            : Afus + (size_t)m_ * 192 + ((KC) - 4) * 64 + ks_ * 32 + g * 8;     \
        A[ks_ * 2 + fm_] = *(const short8*)ap_;                                 \
    } } while (0)

__global__ __launch_bounds__(256, 4) void final7_kernel(
    const u16* __restrict__ Amm, const u16* __restrict__ Afus,
    const u16* __restrict__ vTs,
    const float* __restrict__ xin, const float* __restrict__ yin,
    const float* __restrict__ zin, float* __restrict__ out)
{
    __shared__ u16 Bl[2][128 * 64];

    const int tid = threadIdx.x;
    const int px0 = blockIdx.x * 128;
    const int o0  = blockIdx.y * 128;
    const int b   = blockIdx.z;
    const int lane = tid & 63, wid = tid >> 6;
    const int g = lane >> 4, ln = lane & 15;
    const int m0 = o0 + wid * 32;
    const int pxu = tid & 127;
    const int qq0 = tid >> 7;

    f32x4 acc[2][8] = {};
    short8 aC[4], aN[4];
    uint4 wv[4];
    u32   wx[2][8];

    LOADA_F7(0, aC);
    {
        uint4 v0_[4]; u32 x0_[2][8];
        LOADB_F7(0, v0_, x0_);
        WRITEB_F7(0, 0, v0_, x0_);
    }
    __syncthreads();
    LOADA_F7(1, aN);
    LOADB_F7(1, wv, wx);

    #pragma unroll
    for (int kc = 0; kc < 7; ++kc) {
        const int cur = kc & 1;

        #pragma unroll
        for (int ks = 0; ks < 2; ++ks)
            #pragma unroll
            for (int fn = 0; fn < 8; ++fn) {
                int p = fn * 16 + ln;
                short8 bf = *(const short8*)&Bl[cur][p * 64 + ((ks * 32 + g * 8) ^ ((p & 7) << 3))];
                acc[0][fn] = __builtin_amdgcn_mfma_f32_16x16x32_bf16(aC[ks * 2 + 0], bf, acc[0][fn], 0, 0, 0);
                acc[1][fn] = __builtin_amdgcn_mfma_f32_16x16x32_bf16(aC[ks * 2 + 1], bf, acc[1][fn], 0, 0, 0);
            }

        if (kc < 6) {
            WRITEB_F7(kc + 1, cur ^ 1, wv, wx);
            __syncthreads();
            #pragma unroll
            for (int r = 0; r < 4; ++r) aC[r] = aN[r];
            if (kc < 5) {
                LOADA_F7(kc + 2, aN);
                LOADB_F7(kc + 2, wv, wx);
            }
        }
    }

    // ---- wide store epilogue via LDS reuse (Bl = 32KB = 64x128 f32) ----
    float* Lf = (float*)&Bl[0][0];
    const int wpass = wid >> 1;
    const int chl_base = (wid & 1) * 32;
    float* op = out + (size_t)b * DIM_ * HW_ + px0;

    #pragma unroll
    for (int p = 0; p < 2; ++p) {
        __syncthreads();
        if (wpass == p) {
            #pragma unroll
            for (int fm = 0; fm < 2; ++fm)
                #pragma unroll
                for (int fn = 0; fn < 8; ++fn)
                    #pragma unroll
                    for (int r = 0; r < 4; ++r) {
                        int chl = chl_base + fm * 16 + g * 4 + r;
                        int px = fn * 16 + ln;
                        Lf[chl * 128 + ((px + chl) & 127)] = acc[fm][fn][r];
                    }
        }
        __syncthreads();
        {
            int chl = tid & 63, seg = tid >> 6;
            int cho = o0 + p * 64 + chl;
            float* orow = op + (size_t)cho * HW_ + seg * 32;
            #pragma unroll
            for (int u4 = 0; u4 < 8; ++u4) {
                float4 t;
                t.x = Lf[chl * 128 + ((seg * 32 + u4 * 4 + 0 + chl) & 127)];
                t.y = Lf[chl * 128 + ((seg * 32 + u4 * 4 + 1 + chl) & 127)];
                t.z = Lf[chl * 128 + ((seg * 32 + u4 * 4 + 2 + chl) & 127)];
                t.w = Lf[chl * 128 + ((seg * 32 + u4 * 4 + 3 + chl) & 127)];
                *(float4*)(orow + u4 * 4) = t;
            }
        }
    }
}

// ---------------------------------------------------------------------------
extern "C" void kernel_launch(void* const* d_in, const int* in_sizes, int n_in,
                              void* d_out, int out_size, void* d_ws, size_t ws_size,
                              hipStream_t stream) {
    (void)in_sizes; (void)n_in; (void)out_size; (void)ws_size;

    const float* x     = (const float*)d_in[0];
    const float* y     = (const float*)d_in[1];
    const float* z     = (const float*)d_in[2];
    const float* Wq    = (const float*)d_in[3];
    const float* Wqd   = (const float*)d_in[4];
    const float* Wk    = (const float*)d_in[5];
    const float* Wkd   = (const float*)d_in[6];
    const float* Wv    = (const float*)d_in[7];
    const float* Wvd   = (const float*)d_in[8];
    const float* Wproj = (const float*)d_in[9];
    const float* Wfus  = (const float*)d_in[10];
    const float* temp  = (const float*)d_in[11];

    const size_t QELEMS = (size_t)B_ * DIM_ * HW_;   // 33.5M elems, 64 MiB bf16

    u16* preb = (u16*)d_out;                  // pre_q/pre_k, then preT_v; dead at final
    u16* qbuf = (u16*)d_out + QELEMS;         // q, dead after gram
    u16* kvbuf = (u16*)d_ws;                  // k, then vTs
    char* wsp = (char*)d_ws + QELEMS * sizeof(u16);
    float* pgram = (float*)wsp;                       wsp += 64 * 8 * 1024 * 4;
    float* pssq  = (float*)wsp;                       wsp += 64 * 8 * 32 * 4;
    float* pssk  = (float*)wsp;                       wsp += 64 * 8 * 32 * 4;
    u16*   Amm   = (u16*)wsp;                         wsp += (size_t)B_ * DIM_ * DIM_ * 2;
    u16*   Afus  = (u16*)wsp;

    dim3 cgrid(128, B_);
    dim3 dgrid(4, DIM_, B_);

    wfus_cast_kernel<<<24, 256, 0, stream>>>(Wfus, Afus);
    conv_mfma_kernel<<<cgrid, 256, 0, stream>>>(x, Wq, preb);
    dw_kernel<<<dgrid, 256, 0, stream>>>(preb, Wqd, qbuf);
    conv_mfma_kernel<<<cgrid, 256, 0, stream>>>(y, Wk, preb);
    dw_kernel<<<dgrid, 256, 0, stream>>>(preb, Wkd, kvbuf);
    gram_mfma_kernel<<<dim3(8, 64), 256, 0, stream>>>(qbuf, kvbuf, pgram, pssq, pssk);
    softproj_kernel<<<64, 256, 0, stream>>>(pgram, pssq, pssk, Wproj, temp, Amm);
    conv_mfma_t_kernel<<<cgrid, 256, 0, stream>>>(z, Wv, preb);              // preT
    dwt2_kernel<<<dim3(64, 4, B_), 256, 0, stream>>>(preb, Wvd, kvbuf);      // vTs
    final7_kernel<<<dim3(128, 2, B_), 256, 0, stream>>>(Amm, Afus, kvbuf, x, y, z, (float*)d_out);
}

// Round 11
// 300.938 us; speedup vs baseline: 1.1316x; 1.1316x over previous
//
#include <hip/hip_runtime.h>
#include <cstdint>

#define B_   8
#define CIN  64
#define DIM_ 256
#define H_   128
#define W_   128
#define HW_  (H_*W_)

typedef unsigned short u16;
typedef unsigned int   u32;
typedef short short8 __attribute__((ext_vector_type(8)));
typedef float f32x4  __attribute__((ext_vector_type(4)));

__device__ __forceinline__ u16 f2bf(float f) {
    u32 u = __float_as_uint(f);
    u32 r = (u + 0x7fffu + ((u >> 16) & 1u)) >> 16;
    return (u16)r;
}
__device__ __forceinline__ float bf2f(u16 h) {
    return __uint_as_float(((u32)h) << 16);
}

// ---------------------------------------------------------------------------
// conv1x1 as bf16 MFMA GEMM (R5-proven: 48KB LDS, 3 blocks/CU, scalar stores)
// pre[b][256][HW] = W[256x64] @ in[b][64][HW];  grid (128 px-panels, 8 b)
// ---------------------------------------------------------------------------
__global__ __launch_bounds__(256) void conv_mfma_kernel(
    const float* __restrict__ in, const float* __restrict__ Wc,
    u16* __restrict__ pre)
{
    __shared__ u16 Alds[256 * 64];
    __shared__ u16 Blds[128 * 64];

    const int tid = threadIdx.x;
    const int b = blockIdx.y;
    const int px0 = blockIdx.x * 128;

    {
        const int row = tid;
        const float* wp = Wc + (size_t)row * 64;
        #pragma unroll
        for (int s = 0; s < 8; ++s) {
            float4 f0 = *(const float4*)(wp + s * 8);
            float4 f1 = *(const float4*)(wp + s * 8 + 4);
            uint4 pk;
            pk.x = f2bf(f0.x) | ((u32)f2bf(f0.y) << 16);
            pk.y = f2bf(f0.z) | ((u32)f2bf(f0.w) << 16);
            pk.z = f2bf(f1.x) | ((u32)f2bf(f1.y) << 16);
            pk.w = f2bf(f1.z) | ((u32)f2bf(f1.w) << 16);
            *(uint4*)&Alds[row * 64 + ((s * 8) ^ ((row & 7) << 3))] = pk;
        }
    }
    #pragma unroll
    for (int v4 = 0; v4 < 4; ++v4) {
        int it = tid + v4 * 256;
        int px = it & 127, cg = it >> 7;
        const float* sp = in + ((size_t)b * CIN + cg * 8) * HW_ + px0 + px;
        u32 wv[4];
        #pragma unroll
        for (int j = 0; j < 4; ++j) {
            float a = sp[(size_t)(2 * j) * HW_];
            float c = sp[(size_t)(2 * j + 1) * HW_];
            wv[j] = f2bf(a) | ((u32)f2bf(c) << 16);
        }
        *(uint4*)&Blds[px * 64 + ((cg * 8) ^ ((px & 7) << 3))] =
            make_uint4(wv[0], wv[1], wv[2], wv[3]);
    }
    __syncthreads();

    const int lane = tid & 63, wid = tid >> 6;
    const int g = lane >> 4, ln = lane & 15;
    const int m0 = wid * 64;
    f32x4 acc[4][8] = {};

    #pragma unroll
    for (int ks = 0; ks < 2; ++ks) {
        short8 af[4];
        #pragma unroll
        for (int fm = 0; fm < 4; ++fm) {
            int m = m0 + fm * 16 + ln;
            af[fm] = *(const short8*)&Alds[m * 64 + ((ks * 32 + g * 8) ^ ((m & 7) << 3))];
        }
        #pragma unroll
        for (int fn = 0; fn < 8; ++fn) {
            int p = fn * 16 + ln;
            short8 bf = *(const short8*)&Blds[p * 64 + ((ks * 32 + g * 8) ^ ((p & 7) << 3))];
            #pragma unroll
            for (int fm = 0; fm < 4; ++fm)
                acc[fm][fn] = __builtin_amdgcn_mfma_f32_16x16x32_bf16(af[fm], bf, acc[fm][fn], 0, 0, 0);
        }
    }

    u16* op = pre + (size_t)b * DIM_ * HW_;
    #pragma unroll
    for (int fm = 0; fm < 4; ++fm)
        #pragma unroll
        for (int fn = 0; fn < 8; ++fn)
            #pragma unroll
            for (int r = 0; r < 4; ++r) {
                int ch = m0 + fm * 16 + g * 4 + r;
                op[(size_t)ch * HW_ + px0 + fn * 16 + ln] = f2bf(acc[fm][fn][r]);
            }
}

// ---------------------------------------------------------------------------
// depthwise 3x3 bf16 -> bf16, SAME padding. grid (4 row-strips, 256 ch, 8 b)
// ---------------------------------------------------------------------------
__global__ __launch_bounds__(256) void dw_kernel(
    const u16* __restrict__ pre, const float* __restrict__ Wd,
    u16* __restrict__ dst)
{
    __shared__ u16 t0[34][144];

    const int tid = threadIdx.x;
    const int y0 = blockIdx.x * 32;
    const int ch = blockIdx.y;
    const int b = blockIdx.z;
    const u16* src = pre + ((size_t)b * DIM_ + ch) * HW_;

    for (int i = tid; i < 68; i += 256)
        t0[i >> 1][(i & 1) ? 136 : 7] = 0;
    for (int i = tid; i < 544; i += 256) {
        int row = i >> 4, seg = i & 15;
        int gy = y0 - 1 + row;
        uint4 v = make_uint4(0, 0, 0, 0);
        if (gy >= 0 && gy < H_) v = *(const uint4*)(src + (size_t)gy * W_ + seg * 8);
        *(uint4*)&t0[row][8 + seg * 8] = v;
    }
    const float* wv = Wd + (size_t)ch * 9;
    float w00 = wv[0], w01 = wv[1], w02 = wv[2];
    float w10 = wv[3], w11 = wv[4], w12 = wv[5];
    float w20 = wv[6], w21 = wv[7], w22 = wv[8];
    __syncthreads();

    const int px = tid & 127, half = tid >> 7;
    u16* op = dst + ((size_t)b * DIM_ + ch) * HW_;
    float h0m2 = 0.f, h0m1 = 0.f, h1m1 = 0.f;
    #pragma unroll
    for (int y = 0; y < 18; ++y) {
        int r = half * 16 + y;
        float v0 = bf2f(t0[r][7 + px]);
        float v1 = bf2f(t0[r][8 + px]);
        float v2 = bf2f(t0[r][9 + px]);
        float h0 = fmaf(v0, w00, fmaf(v1, w01, v2 * w02));
        float h1 = fmaf(v0, w10, fmaf(v1, w11, v2 * w12));
        float h2 = fmaf(v0, w20, fmaf(v1, w21, v2 * w22));
        if (y >= 2)
            op[(size_t)(y0 + half * 16 + y - 2) * W_ + px] = f2bf(h0m2 + h1m1 + h2);
        h0m2 = h0m1; h0m1 = h0; h1m1 = h1;
    }
}

// ---------------------------------------------------------------------------
// Gram via MFMA (verified): direct global fragments, sumsq = diagonals
// ---------------------------------------------------------------------------
__global__ __launch_bounds__(256) void gram_mfma_kernel(
    const u16* __restrict__ q, const u16* __restrict__ k,
    float* __restrict__ pgram, float* __restrict__ pssq, float* __restrict__ pssk)
{
    __shared__ float red[4][1024];
    __shared__ float redq[4][32];
    __shared__ float redk[4][32];

    const int bh = blockIdx.y;
    const int chunk = blockIdx.x;
    const int tid = threadIdx.x;
    const int lane = tid & 63, wid = tid >> 6;
    const int g = lane >> 4, ln = lane & 15;

    const size_t off = (size_t)(bh * 32 + ln) * HW_ + chunk * 2048 + wid * 512 + g * 8;
    const u16* qp = q + off;
    const u16* kp = k + off;

    f32x4 aqk[2][2] = {};
    f32x4 aqq[2] = {};
    f32x4 akk[2] = {};

    #pragma unroll 4
    for (int n = 0; n < 512; n += 32) {
        short8 qf[2], kf[2];
        qf[0] = *(const short8*)(qp + n);
        qf[1] = *(const short8*)(qp + (size_t)16 * HW_ + n);
        kf[0] = *(const short8*)(kp + n);
        kf[1] = *(const short8*)(kp + (size_t)16 * HW_ + n);
        #pragma unroll
        for (int ti = 0; ti < 2; ++ti)
            #pragma unroll
            for (int tj = 0; tj < 2; ++tj)
                aqk[ti][tj] = __builtin_amdgcn_mfma_f32_16x16x32_bf16(qf[ti], kf[tj], aqk[ti][tj], 0, 0, 0);
        #pragma unroll
        for (int ti = 0; ti < 2; ++ti) {
            aqq[ti] = __builtin_amdgcn_mfma_f32_16x16x32_bf16(qf[ti], qf[ti], aqq[ti], 0, 0, 0);
            akk[ti] = __builtin_amdgcn_mfma_f32_16x16x32_bf16(kf[ti], kf[ti], akk[ti], 0, 0, 0);
        }
    }

    #pragma unroll
    for (int ti = 0; ti < 2; ++ti)
        #pragma unroll
        for (int tj = 0; tj < 2; ++tj)
            #pragma unroll
            for (int r = 0; r < 4; ++r)
                red[wid][(ti * 16 + g * 4 + r) * 32 + tj * 16 + ln] = aqk[ti][tj][r];
    if ((ln >> 2) == g) {
        #pragma unroll
        for (int ti = 0; ti < 2; ++ti) {
            redq[wid][ti * 16 + ln] = aqq[ti][ln & 3];
            redk[wid][ti * 16 + ln] = akk[ti][ln & 3];
        }
    }
    __syncthreads();

    for (int p = tid; p < 1024; p += 256) {
        float s = red[0][p] + red[1][p] + red[2][p] + red[3][p];
        pgram[((size_t)bh * 8 + chunk) * 1024 + p] = s;
    }
    if (tid < 32) {
        pssq[((size_t)bh * 8 + chunk) * 32 + tid] =
            redq[0][tid] + redq[1][tid] + redq[2][tid] + redq[3][tid];
    } else if (tid < 64) {
        int j = tid & 31;
        pssk[((size_t)bh * 8 + chunk) * 32 + j] =
            redk[0][j] + redk[1][j] + redk[2][j] + redk[3][j];
    }
}

// ---------------------------------------------------------------------------
// reduce partials -> normalize -> softmax -> Amm(bf16) = Wproj_h @ attn
// ---------------------------------------------------------------------------
__global__ __launch_bounds__(256) void softproj_kernel(
    const float* __restrict__ pgram, const float* __restrict__ pssq,
    const float* __restrict__ pssk, const float* __restrict__ Wproj,
    const float* __restrict__ temp, u16* __restrict__ Amm)
{
    __shared__ float att[32][33];
    __shared__ float nq[32], nk[32];

    const int bh = blockIdx.x;
    const int h = bh & 7;
    const int b = bh >> 3;
    const int tid = threadIdx.x;

    for (int p = tid; p < 1024; p += 256) {
        float s = 0.f;
        #pragma unroll
        for (int c = 0; c < 8; ++c) s += pgram[((size_t)bh * 8 + c) * 1024 + p];
        att[p >> 5][p & 31] = s;
    }
    if (tid < 32) {
        float s = 0.f;
        #pragma unroll
        for (int c = 0; c < 8; ++c) s += pssq[((size_t)bh * 8 + c) * 32 + tid];
        nq[tid] = fmaxf(sqrtf(s), 1e-12f);
    } else if (tid < 64) {
        int i = tid & 31;
        float s = 0.f;
        #pragma unroll
        for (int c = 0; c < 8; ++c) s += pssk[((size_t)bh * 8 + c) * 32 + i];
        nk[i] = fmaxf(sqrtf(s), 1e-12f);
    }
    __syncthreads();

    const float T = temp[h];
    if (tid < 32) {
        int i = tid;
        float row[32];
        float mx = -1e30f;
        float qi = T / nq[i];
        #pragma unroll
        for (int j = 0; j < 32; ++j) {
            float v = att[i][j] * qi / nk[j];
            row[j] = v;
            mx = fmaxf(mx, v);
        }
        float s = 0.f;
        #pragma unroll
        for (int j = 0; j < 32; ++j) { float e = expf(row[j] - mx); row[j] = e; s += e; }
        float inv = 1.f / s;
        #pragma unroll
        for (int j = 0; j < 32; ++j) att[i][j] = row[j] * inv;
    }
    __syncthreads();

    const int o = tid;
    float wp[32];
    #pragma unroll
    for (int i2 = 0; i2 < 32; i2 += 4)
        *(float4*)&wp[i2] = *(const float4*)&Wproj[(size_t)o * DIM_ + h * 32 + i2];
    u16* arow = Amm + ((size_t)b * DIM_ + o) * DIM_ + h * 32;
    #pragma unroll
    for (int j = 0; j < 32; ++j) {
        float s = 0.f;
        #pragma unroll
        for (int i = 0; i < 32; ++i) s = fmaf(wp[i], att[i][j], s);
        arow[j] = f2bf(s);
    }
}

// ---------------------------------------------------------------------------
// cast Wfus [256][192] fp32 -> bf16 (once)
// ---------------------------------------------------------------------------
__global__ __launch_bounds__(256) void wfus_cast_kernel(
    const float* __restrict__ Wfus, u16* __restrict__ Afus)
{
    int idx = blockIdx.x * 256 + threadIdx.x;
    int base = idx * 8;
    float4 f0 = *(const float4*)(Wfus + base);
    float4 f1 = *(const float4*)(Wfus + base + 4);
    uint4 pk;
    pk.x = f2bf(f0.x) | ((u32)f2bf(f0.y) << 16);
    pk.y = f2bf(f0.z) | ((u32)f2bf(f0.w) << 16);
    pk.z = f2bf(f1.x) | ((u32)f2bf(f1.y) << 16);
    pk.w = f2bf(f1.z) | ((u32)f2bf(f1.w) << 16);
    *(uint4*)(Afus + base) = pk;
}

// ---------------------------------------------------------------------------
// final4 (R9-proven 86 us): 2 o-groups, 1-deep pipeline, age-ordered
// prefetch, __launch_bounds__(256,4). grid (128 px-panels, 2 o-groups, 8 b)
// ---------------------------------------------------------------------------
#define LOADB_F4(KC, W) do {                                                    \
    if ((KC) < 4) {                                                             \
        _Pragma("unroll") for (int i_ = 0; i_ < 2; ++i_) {                      \
            const u16* vb_ = vbuf + ((size_t)b * DIM_ + (KC) * 64 + (qq0 + 2 * i_) * 16) * HW_ + px0 + pxu; \
            _Pragma("unroll") for (int jj_ = 0; jj_ < 8; ++jj_)                 \
                W[i_][jj_] = (u32)vb_[(size_t)(2 * jj_) * HW_]                  \
                           | ((u32)vb_[(size_t)(2 * jj_ + 1) * HW_] << 16);     \
        }                                                                       \
    } else {                                                                    \
        const float* bp_ = ((KC) == 4) ? xin : ((KC) == 5) ? yin : zin;         \
        _Pragma("unroll") for (int i_ = 0; i_ < 2; ++i_) {                      \
            const float* sp_ = bp_ + ((size_t)b * CIN + (qq0 + 2 * i_) * 16) * HW_ + px0 + pxu; \
            _Pragma("unroll") for (int jj_ = 0; jj_ < 8; ++jj_)                 \
                W[i_][jj_] = (u32)f2bf(sp_[(size_t)(2 * jj_) * HW_])            \
                           | ((u32)f2bf(sp_[(size_t)(2 * jj_ + 1) * HW_]) << 16); \
        }                                                                       \
    } } while (0)

#define WRITEB_F4(BUF, W) do {                                                  \
    u16* dd_ = &Bl[BUF][pxu * 64];                                              \
    _Pragma("unroll") for (int i_ = 0; i_ < 2; ++i_) {                          \
        int qq_ = qq0 + 2 * i_;                                                 \
        *(uint4*)&dd_[(qq_ * 16)     ^ ((pxu & 7) << 3)] = make_uint4(W[i_][0], W[i_][1], W[i_][2], W[i_][3]); \
        *(uint4*)&dd_[(qq_ * 16 + 8) ^ ((pxu & 7) << 3)] = make_uint4(W[i_][4], W[i_][5], W[i_][6], W[i_][7]); \
    } } while (0)

#define LOADA_F4(KC, A) do {                                                    \
    _Pragma("unroll") for (int ks_ = 0; ks_ < 2; ++ks_)                         \
    _Pragma("unroll") for (int fm_ = 0; fm_ < 2; ++fm_) {                       \
        int m_ = m0 + fm_ * 16 + ln;                                            \
        const u16* ap_ = ((KC) < 4)                                             \
            ? Amm + ((size_t)b * DIM_ + m_) * DIM_ + (KC) * 64 + ks_ * 32 + g * 8 \
            : Afus + (size_t)m_ * 192 + ((KC) - 4) * 64 + ks_ * 32 + g * 8;     \
        A[ks_ * 2 + fm_] = *(const short8*)ap_;                                 \
    } } while (0)

__global__ __launch_bounds__(256, 4) void final4_kernel(
    const u16* __restrict__ Amm, const u16* __restrict__ Afus,
    const u16* __restrict__ vbuf,
    const float* __restrict__ xin, const float* __restrict__ yin,
    const float* __restrict__ zin, float* __restrict__ out)
{
    __shared__ u16 Bl[2][128 * 64];

    const int tid = threadIdx.x;
    const int px0 = blockIdx.x * 128;
    const int o0  = blockIdx.y * 128;
    const int b   = blockIdx.z;
    const int lane = tid & 63, wid = tid >> 6;
    const int g = lane >> 4, ln = lane & 15;
    const int m0 = o0 + wid * 32;
    const int pxu = tid & 127;
    const int qq0 = tid >> 7;      // 0 or 1

    f32x4 acc[2][8] = {};
    short8 aC[4], aN[4];
    u32 wN[2][8];

    LOADA_F4(0, aC);
    {
        u32 w0[2][8];
        LOADB_F4(0, w0);
        WRITEB_F4(0, w0);
    }
    __syncthreads();
    LOADA_F4(1, aN);
    LOADB_F4(1, wN);

    #pragma unroll
    for (int kc = 0; kc < 7; ++kc) {
        const int cur = kc & 1;

        #pragma unroll
        for (int ks = 0; ks < 2; ++ks)
            #pragma unroll
            for (int fn = 0; fn < 8; ++fn) {
                int p = fn * 16 + ln;
                short8 bf = *(const short8*)&Bl[cur][p * 64 + ((ks * 32 + g * 8) ^ ((p & 7) << 3))];
                acc[0][fn] = __builtin_amdgcn_mfma_f32_16x16x32_bf16(aC[ks * 2 + 0], bf, acc[0][fn], 0, 0, 0);
                acc[1][fn] = __builtin_amdgcn_mfma_f32_16x16x32_bf16(aC[ks * 2 + 1], bf, acc[1][fn], 0, 0, 0);
            }

        if (kc < 6) {
            WRITEB_F4(cur ^ 1, wN);
            __syncthreads();
            #pragma unroll
            for (int r = 0; r < 4; ++r) aC[r] = aN[r];
            if (kc < 5) {
                LOADA_F4(kc + 2, aN);
                LOADB_F4(kc + 2, wN);
            }
        }
    }

    float* op = out + (size_t)b * DIM_ * HW_;
    #pragma unroll
    for (int fm = 0; fm < 2; ++fm)
        #pragma unroll
        for (int fn = 0; fn < 8; ++fn)
            #pragma unroll
            for (int r = 0; r < 4; ++r) {
                int ch = m0 + fm * 16 + g * 4 + r;
                op[(size_t)ch * HW_ + px0 + fn * 16 + ln] = acc[fm][fn][r];
            }
}

// ---------------------------------------------------------------------------
extern "C" void kernel_launch(void* const* d_in, const int* in_sizes, int n_in,
                              void* d_out, int out_size, void* d_ws, size_t ws_size,
                              hipStream_t stream) {
    (void)in_sizes; (void)n_in; (void)out_size; (void)ws_size;

    const float* x     = (const float*)d_in[0];
    const float* y     = (const float*)d_in[1];
    const float* z     = (const float*)d_in[2];
    const float* Wq    = (const float*)d_in[3];
    const float* Wqd   = (const float*)d_in[4];
    const float* Wk    = (const float*)d_in[5];
    const float* Wkd   = (const float*)d_in[6];
    const float* Wv    = (const float*)d_in[7];
    const float* Wvd   = (const float*)d_in[8];
    const float* Wproj = (const float*)d_in[9];
    const float* Wfus  = (const float*)d_in[10];
    const float* temp  = (const float*)d_in[11];

    const size_t QELEMS = (size_t)B_ * DIM_ * HW_;   // 33.5M elems, 64 MiB bf16

    u16* preb = (u16*)d_out;                  // dead after dw
    u16* qbuf = (u16*)d_out + QELEMS;         // dead after gram
    u16* kvbuf = (u16*)d_ws;                  // k, then v
    char* wsp = (char*)d_ws + QELEMS * sizeof(u16);
    float* pgram = (float*)wsp;                       wsp += 64 * 8 * 1024 * 4;
    float* pssq  = (float*)wsp;                       wsp += 64 * 8 * 32 * 4;
    float* pssk  = (float*)wsp;                       wsp += 64 * 8 * 32 * 4;
    u16*   Amm   = (u16*)wsp;                         wsp += (size_t)B_ * DIM_ * DIM_ * 2;
    u16*   Afus  = (u16*)wsp;

    dim3 cgrid(128, B_);
    dim3 dgrid(4, DIM_, B_);

    wfus_cast_kernel<<<24, 256, 0, stream>>>(Wfus, Afus);
    conv_mfma_kernel<<<cgrid, 256, 0, stream>>>(x, Wq, preb);
    dw_kernel<<<dgrid, 256, 0, stream>>>(preb, Wqd, qbuf);
    conv_mfma_kernel<<<cgrid, 256, 0, stream>>>(y, Wk, preb);
    dw_kernel<<<dgrid, 256, 0, stream>>>(preb, Wkd, kvbuf);
    gram_mfma_kernel<<<dim3(8, 64), 256, 0, stream>>>(qbuf, kvbuf, pgram, pssq, pssk);
    softproj_kernel<<<64, 256, 0, stream>>>(pgram, pssq, pssk, Wproj, temp, Amm);
    conv_mfma_kernel<<<cgrid, 256, 0, stream>>>(z, Wv, preb);
    dw_kernel<<<dgrid, 256, 0, stream>>>(preb, Wvd, kvbuf);
    final4_kernel<<<dim3(128, 2, B_), 256, 0, stream>>>(Amm, Afus, kvbuf, x, y, z, (float*)d_out);
}

// Round 12
// 277.511 us; speedup vs baseline: 1.2272x; 1.0844x over previous
//
#include <hip/hip_runtime.h>
#include <cstdint>

#define B_   8
#define CIN  64
#define DIM_ 256
#define H_   128
#define W_   128
#define HW_  (H_*W_)

typedef unsigned short u16;
typedef unsigned int   u32;
typedef short short8 __attribute__((ext_vector_type(8)));
typedef float f32x4  __attribute__((ext_vector_type(4)));

__device__ __forceinline__ u16 f2bf(float f) {
    u32 u = __float_as_uint(f);
    u32 r = (u + 0x7fffu + ((u >> 16) & 1u)) >> 16;
    return (u16)r;
}
__device__ __forceinline__ float bf2f(u16 h) {
    return __uint_as_float(((u32)h) << 16);
}

// ---------------------------------------------------------------------------
// convdw: FUSED conv1x1(64->256, MFMA) + depthwise3x3, no pre round-trip.
// Per block: 16x16 output tile, ALL 256 out-ch, one batch b.
//   stage W[256][64] + input halo 18x18 px x 64ch as bf16 [px][64k] swizzled
//   loop 4 out-ch chunks: MFMA (M=64,N=336,K=64) -> Pt[64][340] -> dw slide
// grid (64 tiles, 8 b), block 512 (8 waves). LDS ~122 KB -> 1 block/CU.
// ---------------------------------------------------------------------------
__global__ __launch_bounds__(512) void convdw_kernel(
    const float* __restrict__ in, const float* __restrict__ Wc,
    const float* __restrict__ Wd, u16* __restrict__ dst)
{
    __shared__ u16 Wt[256 * 64];     // 32 KB
    __shared__ u16 Xt[336 * 64];     // 43 KB   (px 324..335 unstaged: cols unread)
    __shared__ u16 Pt[64 * 340];     // 43.5 KB (conv out for current chunk)
    __shared__ float wlds[9 * 68];   // 2.4 KB  (dw weights for current chunk)

    const int tid = threadIdx.x;
    const int tile = blockIdx.x;
    const int b = blockIdx.y;
    const int y0 = (tile >> 3) * 16;
    const int x0 = (tile & 7) * 16;

    // ---- stage Wt [256 rows][64 k], conv-proven swizzle ----
    {
        const int row = tid >> 1, hh = tid & 1;   // 2 threads/row
        const float* wp = Wc + (size_t)row * 64 + hh * 32;
        #pragma unroll
        for (int s = 0; s < 4; ++s) {
            float4 f0 = *(const float4*)(wp + s * 8);
            float4 f1 = *(const float4*)(wp + s * 8 + 4);
            uint4 pk;
            pk.x = f2bf(f0.x) | ((u32)f2bf(f0.y) << 16);
            pk.y = f2bf(f0.z) | ((u32)f2bf(f0.w) << 16);
            pk.z = f2bf(f1.x) | ((u32)f2bf(f1.y) << 16);
            pk.w = f2bf(f1.z) | ((u32)f2bf(f1.w) << 16);
            int o = hh * 32 + s * 8;
            *(uint4*)&Wt[row * 64 + (o ^ ((row & 7) << 3))] = pk;
        }
    }
    // ---- stage Xt: halo 324 px x 64 in-ch, [px][64k] swizzled ----
    {
        const float* inb = in + (size_t)b * CIN * HW_;
        for (int i = tid; i < 2592; i += 512) {
            int chg = i / 324;
            int px = i - chg * 324;
            int py = px / 18;
            int pxi = px - py * 18;
            int gy = y0 - 1 + py, gx = x0 - 1 + pxi;
            uint4 pk = make_uint4(0, 0, 0, 0);
            if (gy >= 0 && gy < H_ && gx >= 0 && gx < W_) {
                const float* sp = inb + (size_t)(chg * 8) * HW_ + (size_t)gy * W_ + gx;
                u32 wv[4];
                #pragma unroll
                for (int j = 0; j < 4; ++j) {
                    float a = sp[(size_t)(2 * j) * HW_];
                    float c = sp[(size_t)(2 * j + 1) * HW_];
                    wv[j] = f2bf(a) | ((u32)f2bf(c) << 16);
                }
                pk = make_uint4(wv[0], wv[1], wv[2], wv[3]);
            }
            *(uint4*)&Xt[px * 64 + ((chg * 8) ^ ((px & 7) << 3))] = pk;
        }
    }
    __syncthreads();

    const int lane = tid & 63, w = tid >> 6;
    const int g = lane >> 4, ln = lane & 15;
    const int wm = w & 3;        // m-frag (16 out-ch within chunk)
    const int wpar = w >> 2;     // n-frag parity

    u16* db = dst + (size_t)b * DIM_ * HW_;

    for (int c = 0; c < 4; ++c) {
        // ---- MFMA chunk c: reads only Wt/Xt (stable) -> acc regs ----
        f32x4 acc[11];
        #pragma unroll
        for (int jj = 0; jj < 11; ++jj) acc[jj] = (f32x4){0.f, 0.f, 0.f, 0.f};
        short8 af[2];
        {
            int m = c * 64 + wm * 16 + ln;
            af[0] = *(const short8*)&Wt[m * 64 + ((g * 8) ^ ((m & 7) << 3))];
            af[1] = *(const short8*)&Wt[m * 64 + ((32 + g * 8) ^ ((m & 7) << 3))];
        }
        #pragma unroll
        for (int jj = 0; jj < 11; ++jj) {
            int j = jj * 2 + wpar;
            if (j < 21) {
                int px = j * 16 + ln;
                #pragma unroll
                for (int ks = 0; ks < 2; ++ks) {
                    short8 bf = *(const short8*)&Xt[px * 64 + ((ks * 32 + g * 8) ^ ((px & 7) << 3))];
                    acc[jj] = __builtin_amdgcn_mfma_f32_16x16x32_bf16(af[ks], bf, acc[jj], 0, 0, 0);
                }
            }
        }

        if (c > 0) __syncthreads();   // prev chunk's dw reads of Pt/wlds done

        // ---- write conv result to Pt[64 ch][340] ----
        #pragma unroll
        for (int jj = 0; jj < 11; ++jj) {
            int j = jj * 2 + wpar;
            if (j < 21) {
                int px = j * 16 + ln;
                #pragma unroll
                for (int r = 0; r < 4; ++r)
                    Pt[(wm * 16 + g * 4 + r) * 340 + px] = f2bf(acc[jj][r]);
            }
        }
        // ---- stage dw weights for chunk c ----
        for (int i = tid; i < 576; i += 512) {
            int ch = i / 9, tap = i - ch * 9;
            wlds[tap * 68 + ch] = Wd[(size_t)(c * 64 + ch) * 9 + tap];
        }
        __syncthreads();

        // ---- depthwise 3x3 from Pt (proven sliding window), store to dst ----
        #pragma unroll
        for (int round = 0; round < 2; ++round) {
            int item = tid + round * 512;
            int chl = item >> 4, ox = item & 15;
            float w00 = wlds[0 * 68 + chl], w01 = wlds[1 * 68 + chl], w02 = wlds[2 * 68 + chl];
            float w10 = wlds[3 * 68 + chl], w11 = wlds[4 * 68 + chl], w12 = wlds[5 * 68 + chl];
            float w20 = wlds[6 * 68 + chl], w21 = wlds[7 * 68 + chl], w22 = wlds[8 * 68 + chl];
            const u16* prow = &Pt[chl * 340];
            u16* op = db + (size_t)(c * 64 + chl) * HW_ + x0 + ox;
            float h0m2 = 0.f, h0m1 = 0.f, h1m1 = 0.f;
            #pragma unroll
            for (int hy = 0; hy < 18; ++hy) {
                float v0 = bf2f(prow[hy * 18 + ox]);
                float v1 = bf2f(prow[hy * 18 + ox + 1]);
                float v2 = bf2f(prow[hy * 18 + ox + 2]);
                float h0 = fmaf(v0, w00, fmaf(v1, w01, v2 * w02));
                float h1 = fmaf(v0, w10, fmaf(v1, w11, v2 * w12));
                float h2 = fmaf(v0, w20, fmaf(v1, w21, v2 * w22));
                if (hy >= 2)
                    op[(size_t)(y0 + hy - 2) * W_] = f2bf(h0m2 + h1m1 + h2);
                h0m2 = h0m1; h0m1 = h0; h1m1 = h1;
            }
        }
        if (c == 3) break;
        __syncthreads();   // dw done before next chunk overwrites Pt/wlds
    }
}

// ---------------------------------------------------------------------------
// Gram via MFMA (verified): direct global fragments, sumsq = diagonals
// ---------------------------------------------------------------------------
__global__ __launch_bounds__(256) void gram_mfma_kernel(
    const u16* __restrict__ q, const u16* __restrict__ k,
    float* __restrict__ pgram, float* __restrict__ pssq, float* __restrict__ pssk)
{
    __shared__ float red[4][1024];
    __shared__ float redq[4][32];
    __shared__ float redk[4][32];

    const int bh = blockIdx.y;
    const int chunk = blockIdx.x;
    const int tid = threadIdx.x;
    const int lane = tid & 63, wid = tid >> 6;
    const int g = lane >> 4, ln = lane & 15;

    const size_t off = (size_t)(bh * 32 + ln) * HW_ + chunk * 2048 + wid * 512 + g * 8;
    const u16* qp = q + off;
    const u16* kp = k + off;

    f32x4 aqk[2][2] = {};
    f32x4 aqq[2] = {};
    f32x4 akk[2] = {};

    #pragma unroll 4
    for (int n = 0; n < 512; n += 32) {
        short8 qf[2], kf[2];
        qf[0] = *(const short8*)(qp + n);
        qf[1] = *(const short8*)(qp + (size_t)16 * HW_ + n);
        kf[0] = *(const short8*)(kp + n);
        kf[1] = *(const short8*)(kp + (size_t)16 * HW_ + n);
        #pragma unroll
        for (int ti = 0; ti < 2; ++ti)
            #pragma unroll
            for (int tj = 0; tj < 2; ++tj)
                aqk[ti][tj] = __builtin_amdgcn_mfma_f32_16x16x32_bf16(qf[ti], kf[tj], aqk[ti][tj], 0, 0, 0);
        #pragma unroll
        for (int ti = 0; ti < 2; ++ti) {
            aqq[ti] = __builtin_amdgcn_mfma_f32_16x16x32_bf16(qf[ti], qf[ti], aqq[ti], 0, 0, 0);
            akk[ti] = __builtin_amdgcn_mfma_f32_16x16x32_bf16(kf[ti], kf[ti], akk[ti], 0, 0, 0);
        }
    }

    #pragma unroll
    for (int ti = 0; ti < 2; ++ti)
        #pragma unroll
        for (int tj = 0; tj < 2; ++tj)
            #pragma unroll
            for (int r = 0; r < 4; ++r)
                red[wid][(ti * 16 + g * 4 + r) * 32 + tj * 16 + ln] = aqk[ti][tj][r];
    if ((ln >> 2) == g) {
        #pragma unroll
        for (int ti = 0; ti < 2; ++ti) {
            redq[wid][ti * 16 + ln] = aqq[ti][ln & 3];
            redk[wid][ti * 16 + ln] = akk[ti][ln & 3];
        }
    }
    __syncthreads();

    for (int p = tid; p < 1024; p += 256) {
        float s = red[0][p] + red[1][p] + red[2][p] + red[3][p];
        pgram[((size_t)bh * 8 + chunk) * 1024 + p] = s;
    }
    if (tid < 32) {
        pssq[((size_t)bh * 8 + chunk) * 32 + tid] =
            redq[0][tid] + redq[1][tid] + redq[2][tid] + redq[3][tid];
    } else if (tid < 64) {
        int j = tid & 31;
        pssk[((size_t)bh * 8 + chunk) * 32 + j] =
            redk[0][j] + redk[1][j] + redk[2][j] + redk[3][j];
    }
}

// ---------------------------------------------------------------------------
// reduce partials -> normalize -> softmax -> Amm(bf16) = Wproj_h @ attn
// ---------------------------------------------------------------------------
__global__ __launch_bounds__(256) void softproj_kernel(
    const float* __restrict__ pgram, const float* __restrict__ pssq,
    const float* __restrict__ pssk, const float* __restrict__ Wproj,
    const float* __restrict__ temp, u16* __restrict__ Amm)
{
    __shared__ float att[32][33];
    __shared__ float nq[32], nk[32];

    const int bh = blockIdx.x;
    const int h = bh & 7;
    const int b = bh >> 3;
    const int tid = threadIdx.x;

    for (int p = tid; p < 1024; p += 256) {
        float s = 0.f;
        #pragma unroll
        for (int c = 0; c < 8; ++c) s += pgram[((size_t)bh * 8 + c) * 1024 + p];
        att[p >> 5][p & 31] = s;
    }
    if (tid < 32) {
        float s = 0.f;
        #pragma unroll
        for (int c = 0; c < 8; ++c) s += pssq[((size_t)bh * 8 + c) * 32 + tid];
        nq[tid] = fmaxf(sqrtf(s), 1e-12f);
    } else if (tid < 64) {
        int i = tid & 31;
        float s = 0.f;
        #pragma unroll
        for (int c = 0; c < 8; ++c) s += pssk[((size_t)bh * 8 + c) * 32 + i];
        nk[i] = fmaxf(sqrtf(s), 1e-12f);
    }
    __syncthreads();

    const float T = temp[h];
    if (tid < 32) {
        int i = tid;
        float row[32];
        float mx = -1e30f;
        float qi = T / nq[i];
        #pragma unroll
        for (int j = 0; j < 32; ++j) {
            float v = att[i][j] * qi / nk[j];
            row[j] = v;
            mx = fmaxf(mx, v);
        }
        float s = 0.f;
        #pragma unroll
        for (int j = 0; j < 32; ++j) { float e = expf(row[j] - mx); row[j] = e; s += e; }
        float inv = 1.f / s;
        #pragma unroll
        for (int j = 0; j < 32; ++j) att[i][j] = row[j] * inv;
    }
    __syncthreads();

    const int o = tid;
    float wp[32];
    #pragma unroll
    for (int i2 = 0; i2 < 32; i2 += 4)
        *(float4*)&wp[i2] = *(const float4*)&Wproj[(size_t)o * DIM_ + h * 32 + i2];
    u16* arow = Amm + ((size_t)b * DIM_ + o) * DIM_ + h * 32;
    #pragma unroll
    for (int j = 0; j < 32; ++j) {
        float s = 0.f;
        #pragma unroll
        for (int i = 0; i < 32; ++i) s = fmaf(wp[i], att[i][j], s);
        arow[j] = f2bf(s);
    }
}

// ---------------------------------------------------------------------------
// cast Wfus [256][192] fp32 -> bf16 (once)
// ---------------------------------------------------------------------------
__global__ __launch_bounds__(256) void wfus_cast_kernel(
    const float* __restrict__ Wfus, u16* __restrict__ Afus)
{
    int idx = blockIdx.x * 256 + threadIdx.x;
    int base = idx * 8;
    float4 f0 = *(const float4*)(Wfus + base);
    float4 f1 = *(const float4*)(Wfus + base + 4);
    uint4 pk;
    pk.x = f2bf(f0.x) | ((u32)f2bf(f0.y) << 16);
    pk.y = f2bf(f0.z) | ((u32)f2bf(f0.w) << 16);
    pk.z = f2bf(f1.x) | ((u32)f2bf(f1.y) << 16);
    pk.w = f2bf(f1.z) | ((u32)f2bf(f1.w) << 16);
    *(uint4*)(Afus + base) = pk;
}

// ---------------------------------------------------------------------------
// final4 (R9-proven 86 us): 2 o-groups, 1-deep pipeline, age-ordered
// prefetch, __launch_bounds__(256,4). grid (128 px-panels, 2 o-groups, 8 b)
// ---------------------------------------------------------------------------
#define LOADB_F4(KC, W) do {                                                    \
    if ((KC) < 4) {                                                             \
        _Pragma("unroll") for (int i_ = 0; i_ < 2; ++i_) {                      \
            const u16* vb_ = vbuf + ((size_t)b * DIM_ + (KC) * 64 + (qq0 + 2 * i_) * 16) * HW_ + px0 + pxu; \
            _Pragma("unroll") for (int jj_ = 0; jj_ < 8; ++jj_)                 \
                W[i_][jj_] = (u32)vb_[(size_t)(2 * jj_) * HW_]                  \
                           | ((u32)vb_[(size_t)(2 * jj_ + 1) * HW_] << 16);     \
        }                                                                       \
    } else {                                                                    \
        const float* bp_ = ((KC) == 4) ? xin : ((KC) == 5) ? yin : zin;         \
        _Pragma("unroll") for (int i_ = 0; i_ < 2; ++i_) {                      \
            const float* sp_ = bp_ + ((size_t)b * CIN + (qq0 + 2 * i_) * 16) * HW_ + px0 + pxu; \
            _Pragma("unroll") for (int jj_ = 0; jj_ < 8; ++jj_)                 \
                W[i_][jj_] = (u32)f2bf(sp_[(size_t)(2 * jj_) * HW_])            \
                           | ((u32)f2bf(sp_[(size_t)(2 * jj_ + 1) * HW_]) << 16); \
        }                                                                       \
    } } while (0)

#define WRITEB_F4(BUF, W) do {                                                  \
    u16* dd_ = &Bl[BUF][pxu * 64];                                              \
    _Pragma("unroll") for (int i_ = 0; i_ < 2; ++i_) {                          \
        int qq_ = qq0 + 2 * i_;                                                 \
        *(uint4*)&dd_[(qq_ * 16)     ^ ((pxu & 7) << 3)] = make_uint4(W[i_][0], W[i_][1], W[i_][2], W[i_][3]); \
        *(uint4*)&dd_[(qq_ * 16 + 8) ^ ((pxu & 7) << 3)] = make_uint4(W[i_][4], W[i_][5], W[i_][6], W[i_][7]); \
    } } while (0)

#define LOADA_F4(KC, A) do {                                                    \
    _Pragma("unroll") for (int ks_ = 0; ks_ < 2; ++ks_)                         \
    _Pragma("unroll") for (int fm_ = 0; fm_ < 2; ++fm_) {                       \
        int m_ = m0 + fm_ * 16 + ln;                                            \
        const u16* ap_ = ((KC) < 4)                                             \
            ? Amm + ((size_t)b * DIM_ + m_) * DIM_ + (KC) * 64 + ks_ * 32 + g * 8 \
            : Afus + (size_t)m_ * 192 + ((KC) - 4) * 64 + ks_ * 32 + g * 8;     \
        A[ks_ * 2 + fm_] = *(const short8*)ap_;                                 \
    } } while (0)

__global__ __launch_bounds__(256, 4) void final4_kernel(
    const u16* __restrict__ Amm, const u16* __restrict__ Afus,
    const u16* __restrict__ vbuf,
    const float* __restrict__ xin, const float* __restrict__ yin,
    const float* __restrict__ zin, float* __restrict__ out)
{
    __shared__ u16 Bl[2][128 * 64];

    const int tid = threadIdx.x;
    const int px0 = blockIdx.x * 128;
    const int o0  = blockIdx.y * 128;
    const int b   = blockIdx.z;
    const int lane = tid & 63, wid = tid >> 6;
    const int g = lane >> 4, ln = lane & 15;
    const int m0 = o0 + wid * 32;
    const int pxu = tid & 127;
    const int qq0 = tid >> 7;      // 0 or 1

    f32x4 acc[2][8] = {};
    short8 aC[4], aN[4];
    u32 wN[2][8];

    LOADA_F4(0, aC);
    {
        u32 w0[2][8];
        LOADB_F4(0, w0);
        WRITEB_F4(0, w0);
    }
    __syncthreads();
    LOADA_F4(1, aN);
    LOADB_F4(1, wN);

    #pragma unroll
    for (int kc = 0; kc < 7; ++kc) {
        const int cur = kc & 1;

        #pragma unroll
        for (int ks = 0; ks < 2; ++ks)
            #pragma unroll
            for (int fn = 0; fn < 8; ++fn) {
                int p = fn * 16 + ln;
                short8 bf = *(const short8*)&Bl[cur][p * 64 + ((ks * 32 + g * 8) ^ ((p & 7) << 3))];
                acc[0][fn] = __builtin_amdgcn_mfma_f32_16x16x32_bf16(aC[ks * 2 + 0], bf, acc[0][fn], 0, 0, 0);
                acc[1][fn] = __builtin_amdgcn_mfma_f32_16x16x32_bf16(aC[ks * 2 + 1], bf, acc[1][fn], 0, 0, 0);
            }

        if (kc < 6) {
            WRITEB_F4(cur ^ 1, wN);
            __syncthreads();
            #pragma unroll
            for (int r = 0; r < 4; ++r) aC[r] = aN[r];
            if (kc < 5) {
                LOADA_F4(kc + 2, aN);
                LOADB_F4(kc + 2, wN);
            }
        }
    }

    float* op = out + (size_t)b * DIM_ * HW_;
    #pragma unroll
    for (int fm = 0; fm < 2; ++fm)
        #pragma unroll
        for (int fn = 0; fn < 8; ++fn)
            #pragma unroll
            for (int r = 0; r < 4; ++r) {
                int ch = m0 + fm * 16 + g * 4 + r;
                op[(size_t)ch * HW_ + px0 + fn * 16 + ln] = acc[fm][fn][r];
            }
}

// ---------------------------------------------------------------------------
extern "C" void kernel_launch(void* const* d_in, const int* in_sizes, int n_in,
                              void* d_out, int out_size, void* d_ws, size_t ws_size,
                              hipStream_t stream) {
    (void)in_sizes; (void)n_in; (void)out_size; (void)ws_size;

    const float* x     = (const float*)d_in[0];
    const float* y     = (const float*)d_in[1];
    const float* z     = (const float*)d_in[2];
    const float* Wq    = (const float*)d_in[3];
    const float* Wqd   = (const float*)d_in[4];
    const float* Wk    = (const float*)d_in[5];
    const float* Wkd   = (const float*)d_in[6];
    const float* Wv    = (const float*)d_in[7];
    const float* Wvd   = (const float*)d_in[8];
    const float* Wproj = (const float*)d_in[9];
    const float* Wfus  = (const float*)d_in[10];
    const float* temp  = (const float*)d_in[11];

    const size_t QELEMS = (size_t)B_ * DIM_ * HW_;   // 33.5M elems, 64 MiB bf16

    u16* qbuf = (u16*)d_out + QELEMS;         // q, dead after gram
    u16* kvbuf = (u16*)d_ws;                  // k, then v
    char* wsp = (char*)d_ws + QELEMS * sizeof(u16);
    float* pgram = (float*)wsp;                       wsp += 64 * 8 * 1024 * 4;
    float* pssq  = (float*)wsp;                       wsp += 64 * 8 * 32 * 4;
    float* pssk  = (float*)wsp;                       wsp += 64 * 8 * 32 * 4;
    u16*   Amm   = (u16*)wsp;                         wsp += (size_t)B_ * DIM_ * DIM_ * 2;
    u16*   Afus  = (u16*)wsp;

    dim3 fgrid(64, B_);

    wfus_cast_kernel<<<24, 256, 0, stream>>>(Wfus, Afus);
    convdw_kernel<<<fgrid, 512, 0, stream>>>(x, Wq, Wqd, qbuf);
    convdw_kernel<<<fgrid, 512, 0, stream>>>(y, Wk, Wkd, kvbuf);
    gram_mfma_kernel<<<dim3(8, 64), 256, 0, stream>>>(qbuf, kvbuf, pgram, pssq, pssk);
    softproj_kernel<<<64, 256, 0, stream>>>(pgram, pssq, pssk, Wproj, temp, Amm);
    convdw_kernel<<<fgrid, 512, 0, stream>>>(z, Wv, Wvd, kvbuf);
    final4_kernel<<<dim3(128, 2, B_), 256, 0, stream>>>(Amm, Afus, kvbuf, x, y, z, (float*)d_out);
}

// Round 13
// 265.037 us; speedup vs baseline: 1.2849x; 1.0471x over previous
//
#include <hip/hip_runtime.h>
#include <cstdint>

#define B_   8
#define CIN  64
#define DIM_ 256
#define H_   128
#define W_   128
#define HW_  (H_*W_)

typedef unsigned short u16;
typedef unsigned int   u32;
typedef short short8 __attribute__((ext_vector_type(8)));
typedef float f32x4  __attribute__((ext_vector_type(4)));

__device__ __forceinline__ u16 f2bf(float f) {
    u32 u = __float_as_uint(f);
    u32 r = (u + 0x7fffu + ((u >> 16) & 1u)) >> 16;
    return (u16)r;
}
__device__ __forceinline__ float bf2f(u16 h) {
    return __uint_as_float(((u32)h) << 16);
}

// ---------------------------------------------------------------------------
// convdw v2: FUSED conv1x1 + depthwise3x3, 72.5 KB LDS -> 2 blocks/CU.
// Per block: 16x16 tile, all 256 out-ch in 8 phases of 32 ch; W per-phase
// double-buffered. grid (64 tiles, 8 b) = 512 blocks = exactly co-resident.
// ---------------------------------------------------------------------------
__global__ __launch_bounds__(512) void convdw_kernel(
    const float* __restrict__ in, const float* __restrict__ Wc,
    const float* __restrict__ Wd, u16* __restrict__ dst)
{
    __shared__ u16 Wtc[2][32 * 64];   // 8 KB (double-buffered per-phase W)
    __shared__ u16 Xt[336 * 64];      // 43 KB (halo input, px>=324 unread garbage)
    __shared__ u16 Pt[32 * 340];      // 21.8 KB (conv out, current phase)
    __shared__ float wlds[9 * 36];    // 1.3 KB

    const int tid = threadIdx.x;
    const int tile = blockIdx.x;
    const int b = blockIdx.y;
    const int y0 = (tile >> 3) * 16;
    const int x0 = (tile & 7) * 16;

    // ---- stage Wtc[0] (phase 0: out-ch 0..31) ----
    {
        const int row = tid >> 4, seg = tid & 15;
        float4 f = *(const float4*)(Wc + (size_t)row * 64 + seg * 4);
        uint2 pk;
        pk.x = f2bf(f.x) | ((u32)f2bf(f.y) << 16);
        pk.y = f2bf(f.z) | ((u32)f2bf(f.w) << 16);
        *(uint2*)&Wtc[0][row * 64 + ((seg * 4) ^ ((row & 7) << 3))] = pk;
    }
    // ---- stage Xt: halo 324 px x 64 in-ch, [px][64k] swizzled ----
    {
        const float* inb = in + (size_t)b * CIN * HW_;
        for (int i = tid; i < 2592; i += 512) {
            int chg = i / 324;
            int px = i - chg * 324;
            int py = px / 18;
            int pxi = px - py * 18;
            int gy = y0 - 1 + py, gx = x0 - 1 + pxi;
            uint4 pk = make_uint4(0, 0, 0, 0);
            if (gy >= 0 && gy < H_ && gx >= 0 && gx < W_) {
                const float* sp = inb + (size_t)(chg * 8) * HW_ + (size_t)gy * W_ + gx;
                u32 wv[4];
                #pragma unroll
                for (int j = 0; j < 4; ++j) {
                    float a = sp[(size_t)(2 * j) * HW_];
                    float c = sp[(size_t)(2 * j + 1) * HW_];
                    wv[j] = f2bf(a) | ((u32)f2bf(c) << 16);
                }
                pk = make_uint4(wv[0], wv[1], wv[2], wv[3]);
            }
            *(uint4*)&Xt[px * 64 + ((chg * 8) ^ ((px & 7) << 3))] = pk;
        }
    }
    __syncthreads();

    const int lane = tid & 63, w = tid >> 6;
    const int g = lane >> 4, ln = lane & 15;
    const int wm = w & 1;        // m-frag (16 of 32 out-ch this phase)
    const int wpar = w >> 1;     // n-parity 0..3

    u16* db = dst + (size_t)b * DIM_ * HW_;

    for (int c = 0; c < 8; ++c) {
        const int cb = c & 1;
        // ---- MFMA phase c (reads Wtc[cb], Xt — both stable) ----
        f32x4 acc[6];
        #pragma unroll
        for (int jj = 0; jj < 6; ++jj) acc[jj] = (f32x4){0.f, 0.f, 0.f, 0.f};
        short8 af[2];
        {
            int m = wm * 16 + ln;
            af[0] = *(const short8*)&Wtc[cb][m * 64 + ((g * 8) ^ ((m & 7) << 3))];
            af[1] = *(const short8*)&Wtc[cb][m * 64 + ((32 + g * 8) ^ ((m & 7) << 3))];
        }
        #pragma unroll
        for (int jj = 0; jj < 6; ++jj) {
            int j = jj * 4 + wpar;
            if (j < 21) {
                int px = j * 16 + ln;
                #pragma unroll
                for (int ks = 0; ks < 2; ++ks) {
                    short8 bf = *(const short8*)&Xt[px * 64 + ((ks * 32 + g * 8) ^ ((px & 7) << 3))];
                    acc[jj] = __builtin_amdgcn_mfma_f32_16x16x32_bf16(af[ks], bf, acc[jj], 0, 0, 0);
                }
            }
        }

        // ---- stage next phase's W (buffer last read at MFMA(c-1), safe) ----
        if (c < 7) {
            const int row = tid >> 4, seg = tid & 15;
            float4 f = *(const float4*)(Wc + (size_t)((c + 1) * 32 + row) * 64 + seg * 4);
            uint2 pk;
            pk.x = f2bf(f.x) | ((u32)f2bf(f.y) << 16);
            pk.y = f2bf(f.z) | ((u32)f2bf(f.w) << 16);
            *(uint2*)&Wtc[cb ^ 1][row * 64 + ((seg * 4) ^ ((row & 7) << 3))] = pk;
        }

        // ---- write conv result to Pt (WAR vs dw(c-1) covered by end-sync) ----
        #pragma unroll
        for (int jj = 0; jj < 6; ++jj) {
            int j = jj * 4 + wpar;
            if (j < 21) {
                int px = j * 16 + ln;
                #pragma unroll
                for (int r = 0; r < 4; ++r)
                    Pt[(wm * 16 + g * 4 + r) * 340 + px] = f2bf(acc[jj][r]);
            }
        }
        // ---- stage dw weights for phase c ----
        for (int i = tid; i < 288; i += 512) {
            int ch = i / 9, tap = i - ch * 9;
            wlds[tap * 36 + ch] = Wd[(size_t)(c * 32 + ch) * 9 + tap];
        }
        __syncthreads();

        // ---- depthwise 3x3: 512 items = 32 ch x 16 ox ----
        {
            const int chl = tid >> 4, ox = tid & 15;
            float w00 = wlds[0 * 36 + chl], w01 = wlds[1 * 36 + chl], w02 = wlds[2 * 36 + chl];
            float w10 = wlds[3 * 36 + chl], w11 = wlds[4 * 36 + chl], w12 = wlds[5 * 36 + chl];
            float w20 = wlds[6 * 36 + chl], w21 = wlds[7 * 36 + chl], w22 = wlds[8 * 36 + chl];
            const u16* prow = &Pt[chl * 340];
            u16* op = db + (size_t)(c * 32 + chl) * HW_ + x0 + ox;
            float h0m2 = 0.f, h0m1 = 0.f, h1m1 = 0.f;
            #pragma unroll
            for (int hy = 0; hy < 18; ++hy) {
                float v0 = bf2f(prow[hy * 18 + ox]);
                float v1 = bf2f(prow[hy * 18 + ox + 1]);
                float v2 = bf2f(prow[hy * 18 + ox + 2]);
                float h0 = fmaf(v0, w00, fmaf(v1, w01, v2 * w02));
                float h1 = fmaf(v0, w10, fmaf(v1, w11, v2 * w12));
                float h2 = fmaf(v0, w20, fmaf(v1, w21, v2 * w22));
                if (hy >= 2)
                    op[(size_t)(y0 + hy - 2) * W_] = f2bf(h0m2 + h1m1 + h2);
                h0m2 = h0m1; h0m1 = h0; h1m1 = h1;
            }
        }
        if (c < 7) __syncthreads();   // dw done before Pt/wlds rewritten
    }
}

// ---------------------------------------------------------------------------
// Gram via MFMA (verified): direct global fragments, sumsq = diagonals
// ---------------------------------------------------------------------------
__global__ __launch_bounds__(256) void gram_mfma_kernel(
    const u16* __restrict__ q, const u16* __restrict__ k,
    float* __restrict__ pgram, float* __restrict__ pssq, float* __restrict__ pssk)
{
    __shared__ float red[4][1024];
    __shared__ float redq[4][32];
    __shared__ float redk[4][32];

    const int bh = blockIdx.y;
    const int chunk = blockIdx.x;
    const int tid = threadIdx.x;
    const int lane = tid & 63, wid = tid >> 6;
    const int g = lane >> 4, ln = lane & 15;

    const size_t off = (size_t)(bh * 32 + ln) * HW_ + chunk * 2048 + wid * 512 + g * 8;
    const u16* qp = q + off;
    const u16* kp = k + off;

    f32x4 aqk[2][2] = {};
    f32x4 aqq[2] = {};
    f32x4 akk[2] = {};

    #pragma unroll 4
    for (int n = 0; n < 512; n += 32) {
        short8 qf[2], kf[2];
        qf[0] = *(const short8*)(qp + n);
        qf[1] = *(const short8*)(qp + (size_t)16 * HW_ + n);
        kf[0] = *(const short8*)(kp + n);
        kf[1] = *(const short8*)(kp + (size_t)16 * HW_ + n);
        #pragma unroll
        for (int ti = 0; ti < 2; ++ti)
            #pragma unroll
            for (int tj = 0; tj < 2; ++tj)
                aqk[ti][tj] = __builtin_amdgcn_mfma_f32_16x16x32_bf16(qf[ti], kf[tj], aqk[ti][tj], 0, 0, 0);
        #pragma unroll
        for (int ti = 0; ti < 2; ++ti) {
            aqq[ti] = __builtin_amdgcn_mfma_f32_16x16x32_bf16(qf[ti], qf[ti], aqq[ti], 0, 0, 0);
            akk[ti] = __builtin_amdgcn_mfma_f32_16x16x32_bf16(kf[ti], kf[ti], akk[ti], 0, 0, 0);
        }
    }

    #pragma unroll
    for (int ti = 0; ti < 2; ++ti)
        #pragma unroll
        for (int tj = 0; tj < 2; ++tj)
            #pragma unroll
            for (int r = 0; r < 4; ++r)
                red[wid][(ti * 16 + g * 4 + r) * 32 + tj * 16 + ln] = aqk[ti][tj][r];
    if ((ln >> 2) == g) {
        #pragma unroll
        for (int ti = 0; ti < 2; ++ti) {
            redq[wid][ti * 16 + ln] = aqq[ti][ln & 3];
            redk[wid][ti * 16 + ln] = akk[ti][ln & 3];
        }
    }
    __syncthreads();

    for (int p = tid; p < 1024; p += 256) {
        float s = red[0][p] + red[1][p] + red[2][p] + red[3][p];
        pgram[((size_t)bh * 8 + chunk) * 1024 + p] = s;
    }
    if (tid < 32) {
        pssq[((size_t)bh * 8 + chunk) * 32 + tid] =
            redq[0][tid] + redq[1][tid] + redq[2][tid] + redq[3][tid];
    } else if (tid < 64) {
        int j = tid & 31;
        pssk[((size_t)bh * 8 + chunk) * 32 + j] =
            redk[0][j] + redk[1][j] + redk[2][j] + redk[3][j];
    }
}

// ---------------------------------------------------------------------------
// reduce partials -> normalize -> softmax -> Amm(bf16) = Wproj_h @ attn
// ---------------------------------------------------------------------------
__global__ __launch_bounds__(256) void softproj_kernel(
    const float* __restrict__ pgram, const float* __restrict__ pssq,
    const float* __restrict__ pssk, const float* __restrict__ Wproj,
    const float* __restrict__ temp, u16* __restrict__ Amm)
{
    __shared__ float att[32][33];
    __shared__ float nq[32], nk[32];

    const int bh = blockIdx.x;
    const int h = bh & 7;
    const int b = bh >> 3;
    const int tid = threadIdx.x;

    for (int p = tid; p < 1024; p += 256) {
        float s = 0.f;
        #pragma unroll
        for (int c = 0; c < 8; ++c) s += pgram[((size_t)bh * 8 + c) * 1024 + p];
        att[p >> 5][p & 31] = s;
    }
    if (tid < 32) {
        float s = 0.f;
        #pragma unroll
        for (int c = 0; c < 8; ++c) s += pssq[((size_t)bh * 8 + c) * 32 + tid];
        nq[tid] = fmaxf(sqrtf(s), 1e-12f);
    } else if (tid < 64) {
        int i = tid & 31;
        float s = 0.f;
        #pragma unroll
        for (int c = 0; c < 8; ++c) s += pssk[((size_t)bh * 8 + c) * 32 + i];
        nk[i] = fmaxf(sqrtf(s), 1e-12f);
    }
    __syncthreads();

    const float T = temp[h];
    if (tid < 32) {
        int i = tid;
        float row[32];
        float mx = -1e30f;
        float qi = T / nq[i];
        #pragma unroll
        for (int j = 0; j < 32; ++j) {
            float v = att[i][j] * qi / nk[j];
            row[j] = v;
            mx = fmaxf(mx, v);
        }
        float s = 0.f;
        #pragma unroll
        for (int j = 0; j < 32; ++j) { float e = expf(row[j] - mx); row[j] = e; s += e; }
        float inv = 1.f / s;
        #pragma unroll
        for (int j = 0; j < 32; ++j) att[i][j] = row[j] * inv;
    }
    __syncthreads();

    const int o = tid;
    float wp[32];
    #pragma unroll
    for (int i2 = 0; i2 < 32; i2 += 4)
        *(float4*)&wp[i2] = *(const float4*)&Wproj[(size_t)o * DIM_ + h * 32 + i2];
    u16* arow = Amm + ((size_t)b * DIM_ + o) * DIM_ + h * 32;
    #pragma unroll
    for (int j = 0; j < 32; ++j) {
        float s = 0.f;
        #pragma unroll
        for (int i = 0; i < 32; ++i) s = fmaf(wp[i], att[i][j], s);
        arow[j] = f2bf(s);
    }
}

// ---------------------------------------------------------------------------
// cast Wfus [256][192] fp32 -> bf16 (once)
// ---------------------------------------------------------------------------
__global__ __launch_bounds__(256) void wfus_cast_kernel(
    const float* __restrict__ Wfus, u16* __restrict__ Afus)
{
    int idx = blockIdx.x * 256 + threadIdx.x;
    int base = idx * 8;
    float4 f0 = *(const float4*)(Wfus + base);
    float4 f1 = *(const float4*)(Wfus + base + 4);
    uint4 pk;
    pk.x = f2bf(f0.x) | ((u32)f2bf(f0.y) << 16);
    pk.y = f2bf(f0.z) | ((u32)f2bf(f0.w) << 16);
    pk.z = f2bf(f1.x) | ((u32)f2bf(f1.y) << 16);
    pk.w = f2bf(f1.z) | ((u32)f2bf(f1.w) << 16);
    *(uint4*)(Afus + base) = pk;
}

// ---------------------------------------------------------------------------
// final4 (R9-proven): 2 o-groups, 1-deep pipeline, age-ordered prefetch,
// __launch_bounds__(256,4). grid (128 px-panels, 2 o-groups, 8 b)
// ---------------------------------------------------------------------------
#define LOADB_F4(KC, W) do {                                                    \
    if ((KC) < 4) {                                                             \
        _Pragma("unroll") for (int i_ = 0; i_ < 2; ++i_) {                      \
            const u16* vb_ = vbuf + ((size_t)b * DIM_ + (KC) * 64 + (qq0 + 2 * i_) * 16) * HW_ + px0 + pxu; \
            _Pragma("unroll") for (int jj_ = 0; jj_ < 8; ++jj_)                 \
                W[i_][jj_] = (u32)vb_[(size_t)(2 * jj_) * HW_]                  \
                           | ((u32)vb_[(size_t)(2 * jj_ + 1) * HW_] << 16);     \
        }                                                                       \
    } else {                                                                    \
        const float* bp_ = ((KC) == 4) ? xin : ((KC) == 5) ? yin : zin;         \
        _Pragma("unroll") for (int i_ = 0; i_ < 2; ++i_) {                      \
            const float* sp_ = bp_ + ((size_t)b * CIN + (qq0 + 2 * i_) * 16) * HW_ + px0 + pxu; \
            _Pragma("unroll") for (int jj_ = 0; jj_ < 8; ++jj_)                 \
                W[i_][jj_] = (u32)f2bf(sp_[(size_t)(2 * jj_) * HW_])            \
                           | ((u32)f2bf(sp_[(size_t)(2 * jj_ + 1) * HW_]) << 16); \
        }                                                                       \
    } } while (0)

#define WRITEB_F4(BUF, W) do {                                                  \
    u16* dd_ = &Bl[BUF][pxu * 64];                                              \
    _Pragma("unroll") for (int i_ = 0; i_ < 2; ++i_) {                          \
        int qq_ = qq0 + 2 * i_;                                                 \
        *(uint4*)&dd_[(qq_ * 16)     ^ ((pxu & 7) << 3)] = make_uint4(W[i_][0], W[i_][1], W[i_][2], W[i_][3]); \
        *(uint4*)&dd_[(qq_ * 16 + 8) ^ ((pxu & 7) << 3)] = make_uint4(W[i_][4], W[i_][5], W[i_][6], W[i_][7]); \
    } } while (0)

#define LOADA_F4(KC, A) do {                                                    \
    _Pragma("unroll") for (int ks_ = 0; ks_ < 2; ++ks_)                         \
    _Pragma("unroll") for (int fm_ = 0; fm_ < 2; ++fm_) {                       \
        int m_ = m0 + fm_ * 16 + ln;                                            \
        const u16* ap_ = ((KC) < 4)                                             \
            ? Amm + ((size_t)b * DIM_ + m_) * DIM_ + (KC) * 64 + ks_ * 32 + g * 8 \
            : Afus + (size_t)m_ * 192 + ((KC) - 4) * 64 + ks_ * 32 + g * 8;     \
        A[ks_ * 2 + fm_] = *(const short8*)ap_;                                 \
    } } while (0)

__global__ __launch_bounds__(256, 4) void final4_kernel(
    const u16* __restrict__ Amm, const u16* __restrict__ Afus,
    const u16* __restrict__ vbuf,
    const float* __restrict__ xin, const float* __restrict__ yin,
    const float* __restrict__ zin, float* __restrict__ out)
{
    __shared__ u16 Bl[2][128 * 64];

    const int tid = threadIdx.x;
    const int px0 = blockIdx.x * 128;
    const int o0  = blockIdx.y * 128;
    const int b   = blockIdx.z;
    const int lane = tid & 63, wid = tid >> 6;
    const int g = lane >> 4, ln = lane & 15;
    const int m0 = o0 + wid * 32;
    const int pxu = tid & 127;
    const int qq0 = tid >> 7;      // 0 or 1

    f32x4 acc[2][8] = {};
    short8 aC[4], aN[4];
    u32 wN[2][8];

    LOADA_F4(0, aC);
    {
        u32 w0[2][8];
        LOADB_F4(0, w0);
        WRITEB_F4(0, w0);
    }
    __syncthreads();
    LOADA_F4(1, aN);
    LOADB_F4(1, wN);

    #pragma unroll
    for (int kc = 0; kc < 7; ++kc) {
        const int cur = kc & 1;

        #pragma unroll
        for (int ks = 0; ks < 2; ++ks)
            #pragma unroll
            for (int fn = 0; fn < 8; ++fn) {
                int p = fn * 16 + ln;
                short8 bf = *(const short8*)&Bl[cur][p * 64 + ((ks * 32 + g * 8) ^ ((p & 7) << 3))];
                acc[0][fn] = __builtin_amdgcn_mfma_f32_16x16x32_bf16(aC[ks * 2 + 0], bf, acc[0][fn], 0, 0, 0);
                acc[1][fn] = __builtin_amdgcn_mfma_f32_16x16x32_bf16(aC[ks * 2 + 1], bf, acc[1][fn], 0, 0, 0);
            }

        if (kc < 6) {
            WRITEB_F4(cur ^ 1, wN);
            __syncthreads();
            #pragma unroll
            for (int r = 0; r < 4; ++r) aC[r] = aN[r];
            if (kc < 5) {
                LOADA_F4(kc + 2, aN);
                LOADB_F4(kc + 2, wN);
            }
        }
    }

    float* op = out + (size_t)b * DIM_ * HW_;
    #pragma unroll
    for (int fm = 0; fm < 2; ++fm)
        #pragma unroll
        for (int fn = 0; fn < 8; ++fn)
            #pragma unroll
            for (int r = 0; r < 4; ++r) {
                int ch = m0 + fm * 16 + g * 4 + r;
                op[(size_t)ch * HW_ + px0 + fn * 16 + ln] = acc[fm][fn][r];
            }
}

// ---------------------------------------------------------------------------
extern "C" void kernel_launch(void* const* d_in, const int* in_sizes, int n_in,
                              void* d_out, int out_size, void* d_ws, size_t ws_size,
                              hipStream_t stream) {
    (void)in_sizes; (void)n_in; (void)out_size; (void)ws_size;

    const float* x     = (const float*)d_in[0];
    const float* y     = (const float*)d_in[1];
    const float* z     = (const float*)d_in[2];
    const float* Wq    = (const float*)d_in[3];
    const float* Wqd   = (const float*)d_in[4];
    const float* Wk    = (const float*)d_in[5];
    const float* Wkd   = (const float*)d_in[6];
    const float* Wv    = (const float*)d_in[7];
    const float* Wvd   = (const float*)d_in[8];
    const float* Wproj = (const float*)d_in[9];
    const float* Wfus  = (const float*)d_in[10];
    const float* temp  = (const float*)d_in[11];

    const size_t QELEMS = (size_t)B_ * DIM_ * HW_;   // 33.5M elems, 64 MiB bf16

    u16* qbuf = (u16*)d_out + QELEMS;         // q, dead after gram
    u16* kvbuf = (u16*)d_ws;                  // k, then v
    char* wsp = (char*)d_ws + QELEMS * sizeof(u16);
    float* pgram = (float*)wsp;                       wsp += 64 * 8 * 1024 * 4;
    float* pssq  = (float*)wsp;                       wsp += 64 * 8 * 32 * 4;
    float* pssk  = (float*)wsp;                       wsp += 64 * 8 * 32 * 4;
    u16*   Amm   = (u16*)wsp;                         wsp += (size_t)B_ * DIM_ * DIM_ * 2;
    u16*   Afus  = (u16*)wsp;

    dim3 fgrid(64, B_);

    wfus_cast_kernel<<<24, 256, 0, stream>>>(Wfus, Afus);
    convdw_kernel<<<fgrid, 512, 0, stream>>>(x, Wq, Wqd, qbuf);
    convdw_kernel<<<fgrid, 512, 0, stream>>>(y, Wk, Wkd, kvbuf);
    gram_mfma_kernel<<<dim3(8, 64), 256, 0, stream>>>(qbuf, kvbuf, pgram, pssq, pssk);
    softproj_kernel<<<64, 256, 0, stream>>>(pgram, pssq, pssk, Wproj, temp, Amm);
    convdw_kernel<<<fgrid, 512, 0, stream>>>(z, Wv, Wvd, kvbuf);
    final4_kernel<<<dim3(128, 2, B_), 256, 0, stream>>>(Amm, Afus, kvbuf, x, y, z, (float*)d_out);
}